// Round 4
// baseline (120.858 us; speedup 1.0000x reference)
//
#include <hip/hip_runtime.h>
#include <hip/hip_bf16.h>
#include <cstdint>
#include <cstddef>

namespace {

constexpr int B = 4, N = 128, C = 256, E = 128, O = 128, CH = 8;
constexpr float NEGV = -1.0e9f;

// ---- workspace layout (in float units) ----
// te tensors are stored as bf16 (ushort), 2 ushorts per float slot.
constexpr size_t SZ_TE_F  = (size_t)B * N * N * CH / 2;   // 262144 floats (bf16)
constexpr size_t OFF_TE1T = 0;                             // bf16 [b][j][i][c]
constexpr size_t OFF_TE2  = OFF_TE1T + SZ_TE_F;            // bf16 [b][i][k][c]
constexpr size_t OFF_TE3  = OFF_TE2 + SZ_TE_F;             // bf16 [b][j][k][c] (natural e-layout)
constexpr size_t OFF_M1   = OFF_TE3 + SZ_TE_F;             // f32 m1+mg [b][n][o]
constexpr size_t OFF_M2   = OFF_M1 + (size_t)B * N * O;
constexpr size_t OFF_ZU1  = OFF_M2 + (size_t)B * N * O;    // f32 [b][n][o]
constexpr size_t OFF_T1   = OFF_ZU1 + (size_t)B * N * O;   // f32 [b][n][c]
constexpr size_t OFF_T2   = OFF_T1 + (size_t)B * N * CH;
constexpr size_t OFF_T3   = OFF_T2 + (size_t)B * N * CH;
constexpr size_t OFF_TG   = OFF_T3 + (size_t)B * N * CH;   // f32 [b][c]
constexpr size_t OFF_WT   = OFF_TG + (size_t)B * CH;       // 3 x bf16[O][E]
constexpr size_t OFF_PART = OFF_WT + (size_t)3 * O * E / 2;  // f32 [b][j][4][o]

typedef __attribute__((ext_vector_type(4))) float f32x4;
typedef __attribute__((ext_vector_type(8))) short bf16x8;

__device__ __forceinline__ unsigned short f2b(float f) {
  unsigned u = __float_as_uint(f);
  u = (u + 0x7fffu + ((u >> 16) & 1u)) >> 16;
  return (unsigned short)u;
}
__device__ __forceinline__ float b2f(unsigned short u) {
  return __uint_as_float((unsigned)u << 16);
}

} // namespace

// ---------------------------------------------------------------------------
// K1: small precomputes
// ---------------------------------------------------------------------------
__global__ __launch_bounds__(256) void k_pre(
    const float* __restrict__ z, const float* __restrict__ g,
    const float* __restrict__ Wt1, const float* __restrict__ Wt2,
    const float* __restrict__ Wt3, const float* __restrict__ Wtg,
    const float* __restrict__ Wm1, const float* __restrict__ Wm2,
    const float* __restrict__ Wmg, const float* __restrict__ WU1,
    float* __restrict__ ws) {
  const int blk = blockIdx.x;
  const int b = blk >> 7, n = blk & 127;
  const int t = threadIdx.x;
  __shared__ float zrow[C];
  __shared__ float grow[C / 2];

  for (int k = t; k < C; k += 256) zrow[k] = z[((size_t)(b * N) + n) * C + k];
  if (t < C / 2) grow[t] = g[(size_t)b * (C / 2) + t];
  __syncthreads();

  {
    const int o = t & 127;
    const float* W = (t < 128) ? Wm1 : Wm2;
    float acc = 0.f;
#pragma unroll 8
    for (int k = 0; k < C; ++k) acc += zrow[k] * W[(size_t)k * O + o];
    if (t < 128) {
      float mgacc = 0.f;
      for (int k = 0; k < C / 2; ++k) mgacc += grow[k] * Wmg[(size_t)k * O + o];
      acc += mgacc;
      ws[OFF_M1 + ((size_t)(b * N) + n) * O + o] = acc;
    } else {
      ws[OFF_M2 + ((size_t)(b * N) + n) * O + o] = acc;
    }
  }
  if (t < 128) {
    float acc = 0.f;
#pragma unroll 8
    for (int k = 0; k < C; ++k) acc += zrow[k] * WU1[(size_t)k * O + t];
    ws[OFF_ZU1 + ((size_t)(b * N) + n) * O + t] = acc;
  } else if (t < 152) {
    const int idx = t - 128;
    const int which = idx >> 3, c = idx & 7;
    const float* W = (which == 0) ? Wt1 : ((which == 1) ? Wt2 : Wt3);
    float acc = 0.f;
    for (int k = 0; k < C; ++k) acc += zrow[k] * W[(size_t)k * CH + c];
    const size_t off = (which == 0) ? OFF_T1 : ((which == 1) ? OFF_T2 : OFF_T3);
    ws[off + ((size_t)(b * N) + n) * CH + c] = acc;
  }
  if (n == 0 && t >= 152 && t < 160) {
    const int c = t - 152;
    float acc = 0.f;
    for (int k = 0; k < C / 2; ++k) acc += grow[k] * Wtg[(size_t)k * CH + c];
    ws[OFF_TG + (size_t)b * CH + c] = acc;
  }
}

// ---------------------------------------------------------------------------
// K1b: transpose + bf16 the three msgs-path weights
// ---------------------------------------------------------------------------
__global__ __launch_bounds__(256) void k_wprep(
    const float* __restrict__ Wme, const float* __restrict__ Wmlp1,
    const float* __restrict__ Wmlp2, float* __restrict__ ws) {
  const float* W = (blockIdx.x == 0) ? Wme : ((blockIdx.x == 1) ? Wmlp1 : Wmlp2);
  unsigned short* dst =
      (unsigned short*)(ws + OFF_WT) + (size_t)blockIdx.x * O * E;
  for (int x = threadIdx.x; x < O * E; x += 256) {
    const int o = x >> 7, k = x & 127;
    dst[x] = f2b(W[(size_t)k * O + o]);
  }
}

// ---------------------------------------------------------------------------
// K2: te1^T, te2, te3 = e @ Wte{1,2,3}  (bf16 outputs)
// te1T stored transposed [b][j][i][c]; te2, te3 stored natural [b][i][j][c].
// ---------------------------------------------------------------------------
__global__ __launch_bounds__(256) void k_te(
    const float* __restrict__ e, const float* __restrict__ Wte1,
    const float* __restrict__ Wte2, const float* __restrict__ Wte3,
    float* __restrict__ ws) {
  const int blk = blockIdx.x;
  const int b = blk >> 7, i = blk & 127;
  const int t = threadIdx.x;
  __shared__ float w1[E * CH], w2[E * CH], w3[E * CH];
  __shared__ float ebuf[32][E + 1];
  unsigned short* te1T = (unsigned short*)(ws + OFF_TE1T);
  unsigned short* te2  = (unsigned short*)(ws + OFF_TE2);
  unsigned short* te3  = (unsigned short*)(ws + OFF_TE3);

  for (int x = t; x < E * CH; x += 256) {
    w1[x] = Wte1[x];
    w2[x] = Wte2[x];
    w3[x] = Wte3[x];
  }
  const float* erow = e + ((size_t)(b * N) + i) * N * E;
  const int jj = t >> 3, c = t & 7;

  for (int j0 = 0; j0 < N; j0 += 32) {
    __syncthreads();
    for (int x = t; x < 32 * E; x += 256) {
      const int r = x >> 7, k = x & 127;
      ebuf[r][k] = erow[(size_t)(j0 + r) * E + k];
    }
    __syncthreads();
    float a1 = 0.f, a2 = 0.f, a3 = 0.f;
#pragma unroll 8
    for (int k = 0; k < E; ++k) {
      const float ev = ebuf[jj][k];
      a1 += ev * w1[k * CH + c];
      a2 += ev * w2[k * CH + c];
      a3 += ev * w3[k * CH + c];
    }
    const int j = j0 + jj;
    te1T[(((size_t)(b * N) + j) * N + i) * CH + c] = f2b(a1);
    te2 [(((size_t)(b * N) + i) * N + j) * CH + c] = f2b(a2);
    te3 [(((size_t)(b * N) + i) * N + j) * CH + c] = f2b(a3);  // natural layout (bugfix)
  }
}

// ---------------------------------------------------------------------------
// K3: triplet path, bf16 te inputs.
// ---------------------------------------------------------------------------
__global__ __launch_bounds__(256) void k_tri(
    const float* __restrict__ WU3, const float* __restrict__ ws,
    float* __restrict__ out_tri) {
  const int blk = blockIdx.x;
  const int b = blk >> 7, j = blk & 127;
  const int t = threadIdx.x;
  __shared__ float A[N * CH];
  __shared__ float wu3[CH * O];
  __shared__ float trif[N * CH];
  __shared__ float t2j[CH], tgb[CH];

  const unsigned short* te1Tp =
      (const unsigned short*)(ws + OFF_TE1T) + ((size_t)(b * N) + j) * N * CH;
  const unsigned short* te2p =
      (const unsigned short*)(ws + OFF_TE2) + (size_t)b * N * N * CH;
  const unsigned short* te3p =
      (const unsigned short*)(ws + OFF_TE3) + ((size_t)(b * N) + j) * N * CH;
  const float* t1p = ws + OFF_T1 + (size_t)b * N * CH;
  const float* t3p = ws + OFF_T3 + (size_t)b * N * CH;

  for (int x = t; x < N * CH; x += 256) A[x] = b2f(te1Tp[x]) + t1p[x];
  for (int x = t; x < CH * O; x += 256) wu3[x] = WU3[x];
  if (t < CH) {
    t2j[t] = ws[OFF_T2 + ((size_t)(b * N) + j) * CH + t];
    tgb[t] = ws[OFF_TG + (size_t)b * CH + t];
  }
  __syncthreads();

  // core over elements idx = 4t + p (k = idx>>3, c = idx&7)
  float core[4];
#pragma unroll
  for (int p = 0; p < 4; ++p) core[p] = -3.0e38f;
  for (int i = 0; i < N; ++i) {
    const ushort4 rv = *reinterpret_cast<const ushort4*>(&te2p[(size_t)i * N * CH + t * 4]);
    const float r0 = b2f(rv.x), r1 = b2f(rv.y), r2 = b2f(rv.z), r3 = b2f(rv.w);
    const int c0 = (t * 4) & 7;
    core[0] = fmaxf(core[0], A[i * CH + c0 + 0] + r0);
    core[1] = fmaxf(core[1], A[i * CH + c0 + 1] + r1);
    core[2] = fmaxf(core[2], A[i * CH + c0 + 2] + r2);
    core[3] = fmaxf(core[3], A[i * CH + c0 + 3] + r3);
  }
#pragma unroll
  for (int p = 0; p < 4; ++p) {
    const int idx = t * 4 + p;
    const int k = idx >> 3, c = idx & 7;
    trif[idx] = core[p] + t2j[c] + t3p[k * CH + c] + b2f(te3p[idx]) + tgb[c];
  }
  __syncthreads();

  float* outp = out_tri + ((size_t)(b * N) + j) * N * O;
  for (int q = 0; q < 64; ++q) {
    const int idx = q * 256 + t;
    const int k = idx >> 7, o = idx & 127;
    float acc = 0.f;
#pragma unroll
    for (int c = 0; c < CH; ++c) acc += trif[k * CH + c] * wu3[c * O + o];
    outp[idx] = acc;
  }
}

// ---------------------------------------------------------------------------
// K4: msgs path partial. Grid B*N*4; block (b,j,ig) handles rows
// i in [32*ig, 32*ig+32). 4 waves; wave w owns o-tiles {2w, 2w+1}.
// Writes partial max to ws[OFF_PART].
// ---------------------------------------------------------------------------
__global__ __launch_bounds__(256) void k_msgs(
    const float* __restrict__ e, const void* __restrict__ msk,
    const float* __restrict__ ws_c, float* __restrict__ ws) {
  const int blk = blockIdx.x;
  const int ig = blk & 3, j = (blk >> 2) & 127, b = blk >> 9;
  const int t = threadIdx.x;
  const int i0g = ig * 32;
  constexpr int LDK = 136;
  __shared__ unsigned short act[32 * LDK];  // 8704 B
  __shared__ float m1s[O];
  __shared__ int maskv[32];
  __shared__ int fmt;

  if (t < 64) {
    const unsigned w = ((const unsigned*)msk)[t];
    const float f = __uint_as_float(w);
    const unsigned long long bad_int = __ballot(w > 1u);
    const unsigned long long bad_flt = __ballot(!(f == 0.f || f == 1.f));
    if (t == 0) fmt = (bad_int == 0ull) ? 0 : ((bad_flt == 0ull) ? 2 : 1);
  }
  __syncthreads();
  if (t < 32) {
    const size_t idx = ((size_t)(b * N) + i0g + t) * N + j;
    int mv;
    if (fmt == 0)      mv = ((const int*)msk)[idx] != 0;
    else if (fmt == 1) mv = ((const unsigned char*)msk)[idx] != 0;
    else               mv = ((const float*)msk)[idx] != 0.f;
    maskv[t] = mv;
  }
  if (t >= 128) m1s[t - 128] = ws_c[OFF_M1 + ((size_t)(b * N) + j) * O + (t - 128)];
  __syncthreads();

  // stage masked e[b, i0g+row, j, :] -> bf16 act[row][k]
  const float* ep = e + (((size_t)(b * N) + i0g) * N + j) * E;
  for (int x = t; x < 32 * 32; x += 256) {
    const int row = x >> 5, seg = x & 31;
    const float4 v = *reinterpret_cast<const float4*>(&ep[(size_t)row * N * E + seg * 4]);
    ushort4 pk;
    if (maskv[row]) {
      pk.x = f2b(v.x); pk.y = f2b(v.y); pk.z = f2b(v.z); pk.w = f2b(v.w);
    } else {
      pk.x = pk.y = pk.z = pk.w = 0;
    }
    *reinterpret_cast<ushort4*>(&act[row * LDK + seg * 4]) = pk;
  }
  __syncthreads();

  const int lane = t & 63, wid = t >> 6;
  const int li = lane & 15;
  const int lk8 = (lane >> 4) * 8;
  const int lq4 = (lane >> 4) * 4;

  const unsigned short* wts = (const unsigned short*)(ws_c + OFF_WT);
  const unsigned short* wme_t   = wts;
  const unsigned short* wmlp1_t = wts + (size_t)O * E;
  const unsigned short* wmlp2_t = wts + (size_t)2 * O * E;
  const float* m2p = ws_c + OFF_M2 + (size_t)b * N * O;

  f32x4 acc[2][2];
  bf16x8 af[2][4];

#define LOAD_AF()                                                         \
  _Pragma("unroll") for (int it = 0; it < 2; ++it)                        \
      _Pragma("unroll") for (int kt = 0; kt < 4; ++kt)                    \
          af[it][kt] = *reinterpret_cast<const bf16x8*>(                  \
              &act[(it * 16 + li) * LDK + kt * 32 + lk8]);

#define LAYER(WT)                                                         \
  _Pragma("unroll") for (int it = 0; it < 2; ++it)                        \
      _Pragma("unroll") for (int ol = 0; ol < 2; ++ol)                    \
          acc[it][ol] = (f32x4){0.f, 0.f, 0.f, 0.f};                      \
  _Pragma("unroll") for (int ol = 0; ol < 2; ++ol) {                      \
    const int ot = wid * 2 + ol;                                          \
    _Pragma("unroll") for (int kt = 0; kt < 4; ++kt) {                    \
      const bf16x8 wf = *reinterpret_cast<const bf16x8*>(                 \
          &(WT)[(size_t)(ot * 16 + li) * E + kt * 32 + lk8]);             \
      acc[0][ol] = __builtin_amdgcn_mfma_f32_16x16x32_bf16(               \
          wf, af[0][kt], acc[0][ol], 0, 0, 0);                            \
      acc[1][ol] = __builtin_amdgcn_mfma_f32_16x16x32_bf16(               \
          wf, af[1][kt], acc[1][ol], 0, 0, 0);                            \
    }                                                                     \
  }

  // ===== layer 1: me + m1' + m2, relu =====
  LOAD_AF();
  LAYER(wme_t);
  __syncthreads();  // all reads of act(e) done
#pragma unroll
  for (int it = 0; it < 2; ++it) {
    const int i = it * 16 + li;
#pragma unroll
    for (int ol = 0; ol < 2; ++ol) {
      const int o0 = (wid * 2 + ol) * 16 + lq4;
      const float4 m2v =
          *reinterpret_cast<const float4*>(&m2p[(size_t)(i0g + i) * O + o0]);
      const float4 b1 = *reinterpret_cast<const float4*>(&m1s[o0]);
      ushort4 pk;
      pk.x = f2b(fmaxf(acc[it][ol][0] + m2v.x + b1.x, 0.f));
      pk.y = f2b(fmaxf(acc[it][ol][1] + m2v.y + b1.y, 0.f));
      pk.z = f2b(fmaxf(acc[it][ol][2] + m2v.z + b1.z, 0.f));
      pk.w = f2b(fmaxf(acc[it][ol][3] + m2v.w + b1.w, 0.f));
      *reinterpret_cast<ushort4*>(&act[i * LDK + o0]) = pk;
    }
  }
  __syncthreads();

  // ===== layer 2 =====
  LOAD_AF();
  LAYER(wmlp1_t);
  __syncthreads();
#pragma unroll
  for (int it = 0; it < 2; ++it) {
    const int i = it * 16 + li;
#pragma unroll
    for (int ol = 0; ol < 2; ++ol) {
      const int o0 = (wid * 2 + ol) * 16 + lq4;
      ushort4 pk;
      pk.x = f2b(fmaxf(acc[it][ol][0], 0.f));
      pk.y = f2b(fmaxf(acc[it][ol][1], 0.f));
      pk.z = f2b(fmaxf(acc[it][ol][2], 0.f));
      pk.w = f2b(fmaxf(acc[it][ol][3], 0.f));
      *reinterpret_cast<ushort4*>(&act[i * LDK + o0]) = pk;
    }
  }
  __syncthreads();

  // ===== layer 3: mask -> NEG, max over 32 rows, write partial =====
  LOAD_AF();
  LAYER(wmlp2_t);
  float* part = ws + OFF_PART + (((size_t)(b * N) + j) * 4 + ig) * O;
#pragma unroll
  for (int ol = 0; ol < 2; ++ol) {
    const int ot = wid * 2 + ol;
    float v0, v1, v2, v3;
    {
      const bool ma = maskv[li] != 0, mb = maskv[16 + li] != 0;
      v0 = fmaxf(ma ? acc[0][ol][0] : NEGV, mb ? acc[1][ol][0] : NEGV);
      v1 = fmaxf(ma ? acc[0][ol][1] : NEGV, mb ? acc[1][ol][1] : NEGV);
      v2 = fmaxf(ma ? acc[0][ol][2] : NEGV, mb ? acc[1][ol][2] : NEGV);
      v3 = fmaxf(ma ? acc[0][ol][3] : NEGV, mb ? acc[1][ol][3] : NEGV);
    }
#pragma unroll
    for (int off = 1; off < 16; off <<= 1) {
      v0 = fmaxf(v0, __shfl_xor(v0, off));
      v1 = fmaxf(v1, __shfl_xor(v1, off));
      v2 = fmaxf(v2, __shfl_xor(v2, off));
      v3 = fmaxf(v3, __shfl_xor(v3, off));
    }
    if (li == 0) {
      float4 wv = make_float4(v0, v1, v2, v3);
      *reinterpret_cast<float4*>(&part[ot * 16 + lq4]) = wv;
    }
  }
#undef LOAD_AF
#undef LAYER
}

// ---------------------------------------------------------------------------
// K5: finalize msgs: max over 4 partials -> out_msgs; ret = zU1 + msgs@WU2.
// ---------------------------------------------------------------------------
__global__ __launch_bounds__(256) void k_fin(
    const float* __restrict__ WU2, const float* __restrict__ ws,
    float* __restrict__ out_ret, float* __restrict__ out_msgs) {
  const int blk = blockIdx.x;
  const int b = blk >> 7, j = blk & 127;
  const int t = threadIdx.x;
  __shared__ float msgsrow[O];
  __shared__ float red[2][O];

  const float* part = ws + OFF_PART + ((size_t)(b * N) + j) * 4 * O;
  if (t < O) {
    const float m = fmaxf(fmaxf(part[t], part[O + t]),
                          fmaxf(part[2 * O + t], part[3 * O + t]));
    msgsrow[t] = m;
    out_msgs[((size_t)(b * N) + j) * O + t] = m;
  }
  __syncthreads();

  const int o = t & 127, h = t >> 7;
  float acc = 0.f;
#pragma unroll 8
  for (int p = h * 64; p < h * 64 + 64; ++p)
    acc += msgsrow[p] * WU2[(size_t)p * O + o];
  red[h][o] = acc;
  __syncthreads();
  if (t < O) {
    out_ret[((size_t)(b * N) + j) * O + t] =
        ws[OFF_ZU1 + ((size_t)(b * N) + j) * O + t] + red[0][t] + red[1][t];
  }
}

// ---------------------------------------------------------------------------
extern "C" void kernel_launch(void* const* d_in, const int* in_sizes, int n_in,
                              void* d_out, int out_size, void* d_ws,
                              size_t ws_size, hipStream_t stream) {
  const float* z    = (const float*)d_in[0];
  const float* e    = (const float*)d_in[1];
  const float* g    = (const float*)d_in[2];
  const void*  mmsk = d_in[4];
  const float* Wt1  = (const float*)d_in[5];
  const float* Wt2  = (const float*)d_in[6];
  const float* Wt3  = (const float*)d_in[7];
  const float* Wte1 = (const float*)d_in[8];
  const float* Wte2 = (const float*)d_in[9];
  const float* Wte3 = (const float*)d_in[10];
  const float* Wtg  = (const float*)d_in[11];
  const float* Wm1  = (const float*)d_in[12];
  const float* Wm2  = (const float*)d_in[13];
  const float* Wme  = (const float*)d_in[14];
  const float* Wmg  = (const float*)d_in[15];
  const float* Wmlp1= (const float*)d_in[16];
  const float* Wmlp2= (const float*)d_in[17];
  const float* WU1  = (const float*)d_in[18];
  const float* WU2  = (const float*)d_in[19];
  const float* WU3  = (const float*)d_in[20];

  float* ws = (float*)d_ws;
  float* out_ret  = (float*)d_out;
  float* out_msgs = out_ret + (size_t)B * N * O;
  float* out_tri  = out_msgs + (size_t)B * N * O;

  dim3 blk(256);
  k_pre<<<B * N, blk, 0, stream>>>(z, g, Wt1, Wt2, Wt3, Wtg, Wm1, Wm2, Wmg, WU1, ws);
  k_wprep<<<3, blk, 0, stream>>>(Wme, Wmlp1, Wmlp2, ws);
  k_te<<<B * N, blk, 0, stream>>>(e, Wte1, Wte2, Wte3, ws);
  k_tri<<<B * N, blk, 0, stream>>>(WU3, ws, out_tri);
  k_msgs<<<B * N * 4, blk, 0, stream>>>(e, mmsk, ws, ws);
  k_fin<<<B * N, blk, 0, stream>>>(WU2, ws, out_ret, out_msgs);
}

// Round 5
// 83.633 us; speedup vs baseline: 1.4451x; 1.4451x over previous
//
#include <hip/hip_runtime.h>
#include <hip/hip_bf16.h>
#include <cstdint>
#include <cstddef>

namespace {

constexpr int B = 4, N = 128, C = 256, E = 128, O = 128, CH = 8;
constexpr float NEGV = -1.0e9f;

// ---- workspace layout (in float units) ----
constexpr size_t SZ_TE_F  = (size_t)B * N * N * CH / 2;   // bf16 tensors
constexpr size_t OFF_TE1T = 0;                             // bf16 [b][j][i][c]
constexpr size_t OFF_TE2  = OFF_TE1T + SZ_TE_F;            // bf16 [b][i][k][c]
constexpr size_t OFF_TE3  = OFF_TE2 + SZ_TE_F;             // bf16 [b][j][k][c]
constexpr size_t OFF_M1   = OFF_TE3 + SZ_TE_F;             // f32 m1+mg [b][n][o]
constexpr size_t OFF_M2   = OFF_M1 + (size_t)B * N * O;
constexpr size_t OFF_ZU1  = OFF_M2 + (size_t)B * N * O;    // f32 [b][n][o]
constexpr size_t OFF_T1   = OFF_ZU1 + (size_t)B * N * O;   // f32 [b][n][c]
constexpr size_t OFF_T2   = OFF_T1 + (size_t)B * N * CH;
constexpr size_t OFF_T3   = OFF_T2 + (size_t)B * N * CH;
constexpr size_t OFF_TG   = OFF_T3 + (size_t)B * N * CH;   // f32 [b][c]
constexpr size_t OFF_WT   = OFF_TG + (size_t)B * CH;       // 3 x bf16[O][E]
constexpr size_t OFF_PART = OFF_WT + (size_t)3 * O * E / 2;  // f32 [b][j][4][o]

typedef __attribute__((ext_vector_type(4))) float f32x4;
typedef __attribute__((ext_vector_type(8))) short bf16x8;

__device__ __forceinline__ unsigned short f2b(float f) {
  unsigned u = __float_as_uint(f);
  u = (u + 0x7fffu + ((u >> 16) & 1u)) >> 16;
  return (unsigned short)u;
}
__device__ __forceinline__ float b2f(unsigned short u) {
  return __uint_as_float((unsigned)u << 16);
}

} // namespace

// ---------------------------------------------------------------------------
// Kernel A (prep): fused k_te [0,512) + k_pre [512,1024) + k_wprep [1024,1027)
// ---------------------------------------------------------------------------
__global__ __launch_bounds__(256) void k_prep(
    const float* __restrict__ z, const float* __restrict__ g,
    const float* __restrict__ e,
    const float* __restrict__ Wt1, const float* __restrict__ Wt2,
    const float* __restrict__ Wt3, const float* __restrict__ Wtg,
    const float* __restrict__ Wm1, const float* __restrict__ Wm2,
    const float* __restrict__ Wmg, const float* __restrict__ WU1,
    const float* __restrict__ Wte1, const float* __restrict__ Wte2,
    const float* __restrict__ Wte3,
    const float* __restrict__ Wme, const float* __restrict__ Wmlp1,
    const float* __restrict__ Wmlp2, float* __restrict__ ws) {
  __shared__ __align__(16) char smem[28800];
  const int blk = blockIdx.x;
  const int t = threadIdx.x;

  if (blk < 512) {
    // ===================== te branch =====================
    float* w1 = (float*)(smem);
    float* w2 = (float*)(smem + 4096);
    float* w3 = (float*)(smem + 8192);
    float (*ebuf)[E + 1] = (float (*)[E + 1])(smem + 12288);
    unsigned short* te1T = (unsigned short*)(ws + OFF_TE1T);
    unsigned short* te2  = (unsigned short*)(ws + OFF_TE2);
    unsigned short* te3  = (unsigned short*)(ws + OFF_TE3);
    const int b = blk >> 7, i = blk & 127;

    for (int x = t; x < E * CH; x += 256) {
      w1[x] = Wte1[x];
      w2[x] = Wte2[x];
      w3[x] = Wte3[x];
    }
    const float* erow = e + ((size_t)(b * N) + i) * N * E;
    const int jj = t >> 3, c = t & 7;

    for (int j0 = 0; j0 < N; j0 += 32) {
      __syncthreads();
      for (int x = t; x < 32 * E; x += 256) {
        const int r = x >> 7, k = x & 127;
        ebuf[r][k] = erow[(size_t)(j0 + r) * E + k];
      }
      __syncthreads();
      float a1 = 0.f, a2 = 0.f, a3 = 0.f;
#pragma unroll 8
      for (int k = 0; k < E; ++k) {
        const float ev = ebuf[jj][k];
        a1 += ev * w1[k * CH + c];
        a2 += ev * w2[k * CH + c];
        a3 += ev * w3[k * CH + c];
      }
      const int j = j0 + jj;
      te1T[(((size_t)(b * N) + j) * N + i) * CH + c] = f2b(a1);
      te2 [(((size_t)(b * N) + i) * N + j) * CH + c] = f2b(a2);
      te3 [(((size_t)(b * N) + i) * N + j) * CH + c] = f2b(a3);
    }
  } else if (blk < 1024) {
    // ===================== pre branch =====================
    float* zrow = (float*)(smem);         // 256 f32
    float* grow = (float*)(smem + 1024);  // 128 f32
    const int bn = blk - 512;
    const int b = bn >> 7, n = bn & 127;

    for (int k = t; k < C; k += 256) zrow[k] = z[((size_t)(b * N) + n) * C + k];
    if (t < C / 2) grow[t] = g[(size_t)b * (C / 2) + t];
    __syncthreads();

    {
      const int o = t & 127;
      const float* W = (t < 128) ? Wm1 : Wm2;
      float acc = 0.f;
#pragma unroll 8
      for (int k = 0; k < C; ++k) acc += zrow[k] * W[(size_t)k * O + o];
      if (t < 128) {
        float mgacc = 0.f;
        for (int k = 0; k < C / 2; ++k) mgacc += grow[k] * Wmg[(size_t)k * O + o];
        acc += mgacc;
        ws[OFF_M1 + ((size_t)(b * N) + n) * O + o] = acc;
      } else {
        ws[OFF_M2 + ((size_t)(b * N) + n) * O + o] = acc;
      }
    }
    if (t < 128) {
      float acc = 0.f;
#pragma unroll 8
      for (int k = 0; k < C; ++k) acc += zrow[k] * WU1[(size_t)k * O + t];
      ws[OFF_ZU1 + ((size_t)(b * N) + n) * O + t] = acc;
    } else if (t < 152) {
      const int idx = t - 128;
      const int which = idx >> 3, c = idx & 7;
      const float* W = (which == 0) ? Wt1 : ((which == 1) ? Wt2 : Wt3);
      float acc = 0.f;
      for (int k = 0; k < C; ++k) acc += zrow[k] * W[(size_t)k * CH + c];
      const size_t off = (which == 0) ? OFF_T1 : ((which == 1) ? OFF_T2 : OFF_T3);
      ws[off + ((size_t)(b * N) + n) * CH + c] = acc;
    }
    if (n == 0 && t >= 152 && t < 160) {
      const int c = t - 152;
      float acc = 0.f;
      for (int k = 0; k < C / 2; ++k) acc += grow[k] * Wtg[(size_t)k * CH + c];
      ws[OFF_TG + (size_t)b * CH + c] = acc;
    }
  } else {
    // ===================== wprep branch =====================
    const int which = blk - 1024;
    const float* W = (which == 0) ? Wme : ((which == 1) ? Wmlp1 : Wmlp2);
    unsigned short* dst = (unsigned short*)(ws + OFF_WT) + (size_t)which * O * E;
    for (int x = t; x < O * E; x += 256) {
      const int o = x >> 7, k = x & 127;
      dst[x] = f2b(W[(size_t)k * O + o]);
    }
  }
}

// ---------------------------------------------------------------------------
// Kernel B (main): fused k_msgs [0,2048) + k_tri (k-split x2) [2048,3072)
// ---------------------------------------------------------------------------
__global__ __launch_bounds__(256) void k_main(
    const float* __restrict__ e, const void* __restrict__ msk,
    const float* __restrict__ WU3, const float* __restrict__ ws_c,
    float* __restrict__ ws, float* __restrict__ out_tri) {
  __shared__ __align__(16) char smem[10304];
  const int blk = blockIdx.x;
  const int t = threadIdx.x;

  if (blk < 2048) {
    // ===================== msgs branch =====================
    unsigned short* act = (unsigned short*)(smem);     // 32*136 ushort
    float* m1s = (float*)(smem + 8704);                // 128 f32
    int* maskv = (int*)(smem + 9216);                  // 32 int
    int* fmtp = (int*)(smem + 9344);
    const int ig = blk & 3, j = (blk >> 2) & 127, b = blk >> 9;
    const int i0g = ig * 32;
    constexpr int LDK = 136;

    if (t < 64) {
      const unsigned w = ((const unsigned*)msk)[t];
      const float f = __uint_as_float(w);
      const unsigned long long bad_int = __ballot(w > 1u);
      const unsigned long long bad_flt = __ballot(!(f == 0.f || f == 1.f));
      if (t == 0) *fmtp = (bad_int == 0ull) ? 0 : ((bad_flt == 0ull) ? 2 : 1);
    }
    __syncthreads();
    const int fmt = *fmtp;
    if (t < 32) {
      const size_t idx = ((size_t)(b * N) + i0g + t) * N + j;
      int mv;
      if (fmt == 0)      mv = ((const int*)msk)[idx] != 0;
      else if (fmt == 1) mv = ((const unsigned char*)msk)[idx] != 0;
      else               mv = ((const float*)msk)[idx] != 0.f;
      maskv[t] = mv;
    }
    if (t >= 128) m1s[t - 128] = ws_c[OFF_M1 + ((size_t)(b * N) + j) * O + (t - 128)];
    __syncthreads();

    const float* ep = e + (((size_t)(b * N) + i0g) * N + j) * E;
    for (int x = t; x < 32 * 32; x += 256) {
      const int row = x >> 5, seg = x & 31;
      const float4 v = *reinterpret_cast<const float4*>(&ep[(size_t)row * N * E + seg * 4]);
      ushort4 pk;
      if (maskv[row]) {
        pk.x = f2b(v.x); pk.y = f2b(v.y); pk.z = f2b(v.z); pk.w = f2b(v.w);
      } else {
        pk.x = pk.y = pk.z = pk.w = 0;
      }
      *reinterpret_cast<ushort4*>(&act[row * LDK + seg * 4]) = pk;
    }
    __syncthreads();

    const int lane = t & 63, wid = t >> 6;
    const int li = lane & 15;
    const int lk8 = (lane >> 4) * 8;
    const int lq4 = (lane >> 4) * 4;

    const unsigned short* wts = (const unsigned short*)(ws_c + OFF_WT);
    const unsigned short* wme_t   = wts;
    const unsigned short* wmlp1_t = wts + (size_t)O * E;
    const unsigned short* wmlp2_t = wts + (size_t)2 * O * E;
    const float* m2p = ws_c + OFF_M2 + (size_t)b * N * O;

    f32x4 acc[2][2];
    bf16x8 af[2][4];

#define LOAD_AF()                                                         \
  _Pragma("unroll") for (int it = 0; it < 2; ++it)                        \
      _Pragma("unroll") for (int kt = 0; kt < 4; ++kt)                    \
          af[it][kt] = *reinterpret_cast<const bf16x8*>(                  \
              &act[(it * 16 + li) * LDK + kt * 32 + lk8]);

#define LAYER(WT)                                                         \
  _Pragma("unroll") for (int it = 0; it < 2; ++it)                        \
      _Pragma("unroll") for (int ol = 0; ol < 2; ++ol)                    \
          acc[it][ol] = (f32x4){0.f, 0.f, 0.f, 0.f};                      \
  _Pragma("unroll") for (int ol = 0; ol < 2; ++ol) {                      \
    const int ot = wid * 2 + ol;                                          \
    _Pragma("unroll") for (int kt = 0; kt < 4; ++kt) {                    \
      const bf16x8 wf = *reinterpret_cast<const bf16x8*>(                 \
          &(WT)[(size_t)(ot * 16 + li) * E + kt * 32 + lk8]);             \
      acc[0][ol] = __builtin_amdgcn_mfma_f32_16x16x32_bf16(               \
          wf, af[0][kt], acc[0][ol], 0, 0, 0);                            \
      acc[1][ol] = __builtin_amdgcn_mfma_f32_16x16x32_bf16(               \
          wf, af[1][kt], acc[1][ol], 0, 0, 0);                            \
    }                                                                     \
  }

    // ===== layer 1 =====
    LOAD_AF();
    LAYER(wme_t);
    __syncthreads();
#pragma unroll
    for (int it = 0; it < 2; ++it) {
      const int i = it * 16 + li;
#pragma unroll
      for (int ol = 0; ol < 2; ++ol) {
        const int o0 = (wid * 2 + ol) * 16 + lq4;
        const float4 m2v =
            *reinterpret_cast<const float4*>(&m2p[(size_t)(i0g + i) * O + o0]);
        const float4 b1 = *reinterpret_cast<const float4*>(&m1s[o0]);
        ushort4 pk;
        pk.x = f2b(fmaxf(acc[it][ol][0] + m2v.x + b1.x, 0.f));
        pk.y = f2b(fmaxf(acc[it][ol][1] + m2v.y + b1.y, 0.f));
        pk.z = f2b(fmaxf(acc[it][ol][2] + m2v.z + b1.z, 0.f));
        pk.w = f2b(fmaxf(acc[it][ol][3] + m2v.w + b1.w, 0.f));
        *reinterpret_cast<ushort4*>(&act[i * LDK + o0]) = pk;
      }
    }
    __syncthreads();

    // ===== layer 2 =====
    LOAD_AF();
    LAYER(wmlp1_t);
    __syncthreads();
#pragma unroll
    for (int it = 0; it < 2; ++it) {
      const int i = it * 16 + li;
#pragma unroll
      for (int ol = 0; ol < 2; ++ol) {
        const int o0 = (wid * 2 + ol) * 16 + lq4;
        ushort4 pk;
        pk.x = f2b(fmaxf(acc[it][ol][0], 0.f));
        pk.y = f2b(fmaxf(acc[it][ol][1], 0.f));
        pk.z = f2b(fmaxf(acc[it][ol][2], 0.f));
        pk.w = f2b(fmaxf(acc[it][ol][3], 0.f));
        *reinterpret_cast<ushort4*>(&act[i * LDK + o0]) = pk;
      }
    }
    __syncthreads();

    // ===== layer 3 + masked max + partial write =====
    LOAD_AF();
    LAYER(wmlp2_t);
    float* part = ws + OFF_PART + (((size_t)(b * N) + j) * 4 + ig) * O;
#pragma unroll
    for (int ol = 0; ol < 2; ++ol) {
      const int ot = wid * 2 + ol;
      float v0, v1, v2, v3;
      {
        const bool ma = maskv[li] != 0, mb = maskv[16 + li] != 0;
        v0 = fmaxf(ma ? acc[0][ol][0] : NEGV, mb ? acc[1][ol][0] : NEGV);
        v1 = fmaxf(ma ? acc[0][ol][1] : NEGV, mb ? acc[1][ol][1] : NEGV);
        v2 = fmaxf(ma ? acc[0][ol][2] : NEGV, mb ? acc[1][ol][2] : NEGV);
        v3 = fmaxf(ma ? acc[0][ol][3] : NEGV, mb ? acc[1][ol][3] : NEGV);
      }
#pragma unroll
      for (int off = 1; off < 16; off <<= 1) {
        v0 = fmaxf(v0, __shfl_xor(v0, off));
        v1 = fmaxf(v1, __shfl_xor(v1, off));
        v2 = fmaxf(v2, __shfl_xor(v2, off));
        v3 = fmaxf(v3, __shfl_xor(v3, off));
      }
      if (li == 0) {
        float4 wv = make_float4(v0, v1, v2, v3);
        *reinterpret_cast<float4*>(&part[ot * 16 + lq4]) = wv;
      }
    }
#undef LOAD_AF
#undef LAYER
  } else {
    // ===================== tri branch (k-split) =====================
    float* A    = (float*)(smem);           // [128][8]
    float* wu3  = (float*)(smem + 4096);    // [8][128]
    float* trif = (float*)(smem + 8192);    // [64][8]
    float* t2j  = (float*)(smem + 10240);   // 8
    float* tgb  = (float*)(smem + 10272);   // 8
    const int blk2 = blk - 2048;
    const int kh = blk2 & 1, j = (blk2 >> 1) & 127, b = blk2 >> 8;

    const unsigned short* te1Tp =
        (const unsigned short*)(ws_c + OFF_TE1T) + ((size_t)(b * N) + j) * N * CH;
    const unsigned short* te2p =
        (const unsigned short*)(ws_c + OFF_TE2) + (size_t)b * N * N * CH;
    const unsigned short* te3p =
        (const unsigned short*)(ws_c + OFF_TE3) + ((size_t)(b * N) + j) * N * CH;
    const float* t1p = ws_c + OFF_T1 + (size_t)b * N * CH;
    const float* t3p = ws_c + OFF_T3 + (size_t)b * N * CH;

    for (int x = t; x < N * CH; x += 256) A[x] = b2f(te1Tp[x]) + t1p[x];
    for (int x = t; x < CH * O; x += 256) wu3[x] = WU3[x];
    if (t < CH) {
      t2j[t] = ws_c[OFF_T2 + ((size_t)(b * N) + j) * CH + t];
      tgb[t] = ws_c[OFF_TG + (size_t)b * CH + t];
    }
    __syncthreads();

    // this block handles k in [kh*64, kh*64+64); thread owns elems idx=t*2+{0,1}
    const int kl = t >> 2;            // local k row (0..63)
    const int c0 = (t * 2) & 7;       // channel base (even)
    float core0 = -3.0e38f, core1 = -3.0e38f;
    const size_t base = (size_t)kh * 512 + t * 2;
    for (int i = 0; i < N; i += 2) {
      const ushort2 ra = *reinterpret_cast<const ushort2*>(&te2p[(size_t)i * N * CH + base]);
      const ushort2 rb = *reinterpret_cast<const ushort2*>(&te2p[(size_t)(i + 1) * N * CH + base]);
      const float a0 = A[i * CH + c0], a1 = A[i * CH + c0 + 1];
      const float b0 = A[(i + 1) * CH + c0], b1 = A[(i + 1) * CH + c0 + 1];
      core0 = fmaxf(core0, a0 + b2f(ra.x));
      core1 = fmaxf(core1, a1 + b2f(ra.y));
      core0 = fmaxf(core0, b0 + b2f(rb.x));
      core1 = fmaxf(core1, b1 + b2f(rb.y));
    }
    const int kg = kh * 64 + kl;
    trif[kl * CH + c0]     = core0 + t2j[c0] + t3p[kg * CH + c0] + b2f(te3p[kg * CH + c0]) + tgb[c0];
    trif[kl * CH + c0 + 1] = core1 + t2j[c0 + 1] + t3p[kg * CH + c0 + 1] + b2f(te3p[kg * CH + c0 + 1]) + tgb[c0 + 1];
    __syncthreads();

    float* outp = out_tri + ((size_t)(b * N) + j) * N * O;
    for (int q = 0; q < 32; ++q) {
      const int idx = q * 256 + t;
      const int klr = idx >> 7, o = idx & 127;
      float acc = 0.f;
#pragma unroll
      for (int c = 0; c < CH; ++c) acc += trif[klr * CH + c] * wu3[c * O + o];
      outp[(size_t)(kh * 64 + klr) * O + o] = acc;
    }
  }
}

// ---------------------------------------------------------------------------
// Kernel C: finalize msgs + ret
// ---------------------------------------------------------------------------
__global__ __launch_bounds__(256) void k_fin(
    const float* __restrict__ WU2, const float* __restrict__ ws,
    float* __restrict__ out_ret, float* __restrict__ out_msgs) {
  const int blk = blockIdx.x;
  const int b = blk >> 7, j = blk & 127;
  const int t = threadIdx.x;
  __shared__ float msgsrow[O];
  __shared__ float red[2][O];

  const float* part = ws + OFF_PART + ((size_t)(b * N) + j) * 4 * O;
  if (t < O) {
    const float m = fmaxf(fmaxf(part[t], part[O + t]),
                          fmaxf(part[2 * O + t], part[3 * O + t]));
    msgsrow[t] = m;
    out_msgs[((size_t)(b * N) + j) * O + t] = m;
  }
  __syncthreads();

  const int o = t & 127, h = t >> 7;
  float acc = 0.f;
#pragma unroll 8
  for (int p = h * 64; p < h * 64 + 64; ++p)
    acc += msgsrow[p] * WU2[(size_t)p * O + o];
  red[h][o] = acc;
  __syncthreads();
  if (t < O) {
    out_ret[((size_t)(b * N) + j) * O + t] =
        ws[OFF_ZU1 + ((size_t)(b * N) + j) * O + t] + red[0][t] + red[1][t];
  }
}

// ---------------------------------------------------------------------------
extern "C" void kernel_launch(void* const* d_in, const int* in_sizes, int n_in,
                              void* d_out, int out_size, void* d_ws,
                              size_t ws_size, hipStream_t stream) {
  const float* z    = (const float*)d_in[0];
  const float* e    = (const float*)d_in[1];
  const float* g    = (const float*)d_in[2];
  const void*  mmsk = d_in[4];
  const float* Wt1  = (const float*)d_in[5];
  const float* Wt2  = (const float*)d_in[6];
  const float* Wt3  = (const float*)d_in[7];
  const float* Wte1 = (const float*)d_in[8];
  const float* Wte2 = (const float*)d_in[9];
  const float* Wte3 = (const float*)d_in[10];
  const float* Wtg  = (const float*)d_in[11];
  const float* Wm1  = (const float*)d_in[12];
  const float* Wm2  = (const float*)d_in[13];
  const float* Wme  = (const float*)d_in[14];
  const float* Wmg  = (const float*)d_in[15];
  const float* Wmlp1= (const float*)d_in[16];
  const float* Wmlp2= (const float*)d_in[17];
  const float* WU1  = (const float*)d_in[18];
  const float* WU2  = (const float*)d_in[19];
  const float* WU3  = (const float*)d_in[20];

  float* ws = (float*)d_ws;
  float* out_ret  = (float*)d_out;
  float* out_msgs = out_ret + (size_t)B * N * O;
  float* out_tri  = out_msgs + (size_t)B * N * O;

  dim3 blk(256);
  k_prep<<<1027, blk, 0, stream>>>(z, g, e, Wt1, Wt2, Wt3, Wtg, Wm1, Wm2, Wmg,
                                   WU1, Wte1, Wte2, Wte3, Wme, Wmlp1, Wmlp2, ws);
  k_main<<<3072, blk, 0, stream>>>(e, mmsk, WU3, ws, ws, out_tri);
  k_fin<<<B * N, blk, 0, stream>>>(WU2, ws, out_ret, out_msgs);
}

// Round 6
// 83.571 us; speedup vs baseline: 1.4462x; 1.0007x over previous
//
#include <hip/hip_runtime.h>
#include <hip/hip_bf16.h>
#include <cstdint>
#include <cstddef>

namespace {

constexpr int B = 4, N = 128, C = 256, E = 128, O = 128, CH = 8;
constexpr float NEGV = -1.0e9f;

// ---- workspace layout (in float units) ----
constexpr size_t SZ_TE_F  = (size_t)B * N * N * CH / 2;   // bf16 tensors
constexpr size_t OFF_TE1T = 0;                             // bf16 [b][j][i][c]
constexpr size_t OFF_TE2  = OFF_TE1T + SZ_TE_F;            // bf16 [b][i][k][c]
constexpr size_t OFF_TE3  = OFF_TE2 + SZ_TE_F;             // bf16 [b][j][k][c]
constexpr size_t OFF_M1   = OFF_TE3 + SZ_TE_F;             // f32 m1+mg [b][n][o]
constexpr size_t OFF_M2   = OFF_M1 + (size_t)B * N * O;
constexpr size_t OFF_ZU1  = OFF_M2 + (size_t)B * N * O;    // f32 [b][n][o]
constexpr size_t OFF_T1   = OFF_ZU1 + (size_t)B * N * O;   // f32 [b][n][c]
constexpr size_t OFF_T2   = OFF_T1 + (size_t)B * N * CH;
constexpr size_t OFF_T3   = OFF_T2 + (size_t)B * N * CH;
constexpr size_t OFF_TG   = OFF_T3 + (size_t)B * N * CH;   // f32 [b][c]
constexpr size_t OFF_WT   = OFF_TG + (size_t)B * CH;       // 3 x bf16[O][E]
constexpr size_t OFF_PART = OFF_WT + (size_t)3 * O * E / 2;  // f32 [b][j][4][o]

typedef __attribute__((ext_vector_type(4))) float f32x4;
typedef __attribute__((ext_vector_type(8))) short bf16x8;
typedef __attribute__((ext_vector_type(8))) unsigned short u16x8;

__device__ __forceinline__ unsigned short f2b(float f) {
  unsigned u = __float_as_uint(f);
  u = (u + 0x7fffu + ((u >> 16) & 1u)) >> 16;
  return (unsigned short)u;
}
__device__ __forceinline__ float b2f(unsigned short u) {
  return __uint_as_float((unsigned)u << 16);
}

} // namespace

// ---------------------------------------------------------------------------
// Kernel A (prep): fused te-MFMA [0,512) + pre [512,1024) + wprep [1024,1027)
// ---------------------------------------------------------------------------
__global__ __launch_bounds__(256) void k_prep(
    const float* __restrict__ z, const float* __restrict__ g,
    const float* __restrict__ e,
    const float* __restrict__ Wt1, const float* __restrict__ Wt2,
    const float* __restrict__ Wt3, const float* __restrict__ Wtg,
    const float* __restrict__ Wm1, const float* __restrict__ Wm2,
    const float* __restrict__ Wmg, const float* __restrict__ WU1,
    const float* __restrict__ Wte1, const float* __restrict__ Wte2,
    const float* __restrict__ Wte3,
    const float* __restrict__ Wme, const float* __restrict__ Wmlp1,
    const float* __restrict__ Wmlp2, float* __restrict__ ws) {
  __shared__ __align__(16) char smem[25600];
  const int blk = blockIdx.x;
  const int t = threadIdx.x;

  if (blk < 512) {
    // ============ te branch (MFMA): [te1|te2|te3](j,c) for one (b,i) ========
    unsigned short* wpack = (unsigned short*)(smem);            // [32][136]
    unsigned short* ebuf  = (unsigned short*)(smem + 8704);     // [32][136]
    unsigned short* outl  = (unsigned short*)(smem + 17408);    // [128][32]
    unsigned short* te1T = (unsigned short*)(ws + OFF_TE1T);
    unsigned short* te2  = (unsigned short*)(ws + OFF_TE2);
    unsigned short* te3  = (unsigned short*)(ws + OFF_TE3);
    const int b = blk >> 7, i = blk & 127;

    // stage packed transposed weights: wpack[m*8+c][k] = Wte_m[k][c]
    for (int x = t; x < 3072; x += 256) {
      const int m = x >> 10, rem = x & 1023, k = rem >> 3, c = rem & 7;
      const float* W = (m == 0) ? Wte1 : ((m == 1) ? Wte2 : Wte3);
      wpack[(m * 8 + c) * 136 + k] = f2b(W[rem]);
    }
    for (int x = t; x < 1024; x += 256)
      wpack[(24 + (x >> 7)) * 136 + (x & 127)] = 0;  // pad rows 24..31

    const float* erow = e + ((size_t)(b * N) + i) * N * E;
    const int lane = t & 63, wid = t >> 6;
    const int li = lane & 15, lk8 = (lane >> 4) * 8, lq4 = (lane >> 4) * 4;
    const int jt = wid & 1, ct = wid >> 1;

    for (int j0 = 0; j0 < N; j0 += 32) {
      __syncthreads();
      for (int x = t; x < 1024; x += 256) {
        const int r = x >> 5, seg = x & 31;
        const float4 v = *reinterpret_cast<const float4*>(
            &erow[(size_t)(j0 + r) * E + seg * 4]);
        ushort4 pk;
        pk.x = f2b(v.x); pk.y = f2b(v.y); pk.z = f2b(v.z); pk.w = f2b(v.w);
        *reinterpret_cast<ushort4*>(&ebuf[r * 136 + seg * 4]) = pk;
      }
      __syncthreads();
      f32x4 acc = {0.f, 0.f, 0.f, 0.f};
#pragma unroll
      for (int kt = 0; kt < 4; ++kt) {
        const bf16x8 wf = *reinterpret_cast<const bf16x8*>(
            &wpack[(ct * 16 + li) * 136 + kt * 32 + lk8]);
        const bf16x8 af = *reinterpret_cast<const bf16x8*>(
            &ebuf[(jt * 16 + li) * 136 + kt * 32 + lk8]);
        acc = __builtin_amdgcn_mfma_f32_16x16x32_bf16(wf, af, acc, 0, 0, 0);
      }
      const int c0 = ct * 16 + lq4;
      if (c0 < 24) {
        ushort4 pk;
        pk.x = f2b(acc[0]); pk.y = f2b(acc[1]);
        pk.z = f2b(acc[2]); pk.w = f2b(acc[3]);
        *reinterpret_cast<ushort4*>(&outl[(j0 + jt * 16 + li) * 32 + c0]) = pk;
      }
    }
    __syncthreads();
    for (int x = t; x < 384; x += 256) {
      const int m = x >> 7, j = x & 127;
      const u16x8 v = *reinterpret_cast<const u16x8*>(&outl[j * 32 + m * 8]);
      if (m == 0)
        *reinterpret_cast<u16x8*>(&te1T[(((size_t)(b * N) + j) * N + i) * CH]) = v;
      else if (m == 1)
        *reinterpret_cast<u16x8*>(&te2[(((size_t)(b * N) + i) * N + j) * CH]) = v;
      else
        *reinterpret_cast<u16x8*>(&te3[(((size_t)(b * N) + i) * N + j) * CH]) = v;
    }
  } else if (blk < 1024) {
    // ===================== pre branch =====================
    float* zrow = (float*)(smem);
    float* grow = (float*)(smem + 1024);
    const int bn = blk - 512;
    const int b = bn >> 7, n = bn & 127;

    for (int k = t; k < C; k += 256) zrow[k] = z[((size_t)(b * N) + n) * C + k];
    if (t < C / 2) grow[t] = g[(size_t)b * (C / 2) + t];
    __syncthreads();

    {
      const int o = t & 127;
      const float* W = (t < 128) ? Wm1 : Wm2;
      float acc = 0.f;
#pragma unroll 8
      for (int k = 0; k < C; ++k) acc += zrow[k] * W[(size_t)k * O + o];
      if (t < 128) {
        float mgacc = 0.f;
        for (int k = 0; k < C / 2; ++k) mgacc += grow[k] * Wmg[(size_t)k * O + o];
        acc += mgacc;
        ws[OFF_M1 + ((size_t)(b * N) + n) * O + o] = acc;
      } else {
        ws[OFF_M2 + ((size_t)(b * N) + n) * O + o] = acc;
      }
    }
    if (t < 128) {
      float acc = 0.f;
#pragma unroll 8
      for (int k = 0; k < C; ++k) acc += zrow[k] * WU1[(size_t)k * O + t];
      ws[OFF_ZU1 + ((size_t)(b * N) + n) * O + t] = acc;
    } else if (t < 152) {
      const int idx = t - 128;
      const int which = idx >> 3, c = idx & 7;
      const float* W = (which == 0) ? Wt1 : ((which == 1) ? Wt2 : Wt3);
      float acc = 0.f;
      for (int k = 0; k < C; ++k) acc += zrow[k] * W[(size_t)k * CH + c];
      const size_t off = (which == 0) ? OFF_T1 : ((which == 1) ? OFF_T2 : OFF_T3);
      ws[off + ((size_t)(b * N) + n) * CH + c] = acc;
    }
    if (n == 0 && t >= 152 && t < 160) {
      const int c = t - 152;
      float acc = 0.f;
      for (int k = 0; k < C / 2; ++k) acc += grow[k] * Wtg[(size_t)k * CH + c];
      ws[OFF_TG + (size_t)b * CH + c] = acc;
    }
  } else {
    // ===================== wprep branch =====================
    const int which = blk - 1024;
    const float* W = (which == 0) ? Wme : ((which == 1) ? Wmlp1 : Wmlp2);
    unsigned short* dst = (unsigned short*)(ws + OFF_WT) + (size_t)which * O * E;
    for (int x = t; x < O * E; x += 256) {
      const int o = x >> 7, k = x & 127;
      dst[x] = f2b(W[(size_t)k * O + o]);
    }
  }
}

// ---------------------------------------------------------------------------
// Kernel B (main): fused msgs [0,2048) + tri (k-quarter split) [2048,4096)
// ---------------------------------------------------------------------------
__global__ __launch_bounds__(256) void k_main(
    const float* __restrict__ e, const void* __restrict__ msk,
    const float* __restrict__ WU3, const float* __restrict__ ws_c,
    float* __restrict__ ws, float* __restrict__ out_tri) {
  __shared__ __align__(16) char smem[10304];
  const int blk = blockIdx.x;
  const int t = threadIdx.x;

  if (blk < 2048) {
    // ===================== msgs branch =====================
    unsigned short* act = (unsigned short*)(smem);     // [32][136]
    float* m1s = (float*)(smem + 8704);                // 128 f32
    int* maskv = (int*)(smem + 9216);                  // 32 int
    int* fmtp = (int*)(smem + 9344);
    const int ig = blk & 3, j = (blk >> 2) & 127, b = blk >> 9;
    const int i0g = ig * 32;
    constexpr int LDK = 136;

    const int lane = t & 63, wid = t >> 6;
    const int li = lane & 15;
    const int lk8 = (lane >> 4) * 8;
    const int lq4 = (lane >> 4) * 4;

    const unsigned short* wts = (const unsigned short*)(ws_c + OFF_WT);
    const unsigned short* wme_t   = wts;
    const unsigned short* wmlp1_t = wts + (size_t)O * E;
    const unsigned short* wmlp2_t = wts + (size_t)2 * O * E;
    const float* m2p = ws_c + OFF_M2 + (size_t)b * N * O;

    f32x4 acc[2][2];
    bf16x8 af[2][4];
    bf16x8 wfA[8], wfB[8];

#define PRELOAD(WT, wf)                                                   \
  _Pragma("unroll") for (int ol = 0; ol < 2; ++ol)                        \
      _Pragma("unroll") for (int kt = 0; kt < 4; ++kt)                    \
          wf[ol * 4 + kt] = *reinterpret_cast<const bf16x8*>(             \
              &(WT)[(size_t)((wid * 2 + ol) * 16 + li) * E + kt * 32 + lk8]);

#define LOAD_AF()                                                         \
  _Pragma("unroll") for (int it = 0; it < 2; ++it)                        \
      _Pragma("unroll") for (int kt = 0; kt < 4; ++kt)                    \
          af[it][kt] = *reinterpret_cast<const bf16x8*>(                  \
              &act[(it * 16 + li) * LDK + kt * 32 + lk8]);

#define LAYER_PRE(wf)                                                     \
  _Pragma("unroll") for (int it = 0; it < 2; ++it)                        \
      _Pragma("unroll") for (int ol = 0; ol < 2; ++ol)                    \
          acc[it][ol] = (f32x4){0.f, 0.f, 0.f, 0.f};                      \
  _Pragma("unroll") for (int ol = 0; ol < 2; ++ol) {                      \
    _Pragma("unroll") for (int kt = 0; kt < 4; ++kt) {                    \
      acc[0][ol] = __builtin_amdgcn_mfma_f32_16x16x32_bf16(               \
          wf[ol * 4 + kt], af[0][kt], acc[0][ol], 0, 0, 0);               \
      acc[1][ol] = __builtin_amdgcn_mfma_f32_16x16x32_bf16(               \
          wf[ol * 4 + kt], af[1][kt], acc[1][ol], 0, 0, 0);               \
    }                                                                     \
  }

    PRELOAD(wme_t, wfA);  // issue layer-1 weights early

    if (t < 64) {
      const unsigned w = ((const unsigned*)msk)[t];
      const float f = __uint_as_float(w);
      const unsigned long long bad_int = __ballot(w > 1u);
      const unsigned long long bad_flt = __ballot(!(f == 0.f || f == 1.f));
      if (t == 0) *fmtp = (bad_int == 0ull) ? 0 : ((bad_flt == 0ull) ? 2 : 1);
    }
    __syncthreads();
    const int fmt = *fmtp;
    if (t < 32) {
      const size_t idx = ((size_t)(b * N) + i0g + t) * N + j;
      int mv;
      if (fmt == 0)      mv = ((const int*)msk)[idx] != 0;
      else if (fmt == 1) mv = ((const unsigned char*)msk)[idx] != 0;
      else               mv = ((const float*)msk)[idx] != 0.f;
      maskv[t] = mv;
    }
    if (t >= 128) m1s[t - 128] = ws_c[OFF_M1 + ((size_t)(b * N) + j) * O + (t - 128)];
    __syncthreads();

    const float* ep = e + (((size_t)(b * N) + i0g) * N + j) * E;
    for (int x = t; x < 32 * 32; x += 256) {
      const int row = x >> 5, seg = x & 31;
      const float4 v = *reinterpret_cast<const float4*>(&ep[(size_t)row * N * E + seg * 4]);
      ushort4 pk;
      if (maskv[row]) {
        pk.x = f2b(v.x); pk.y = f2b(v.y); pk.z = f2b(v.z); pk.w = f2b(v.w);
      } else {
        pk.x = pk.y = pk.z = pk.w = 0;
      }
      *reinterpret_cast<ushort4*>(&act[row * LDK + seg * 4]) = pk;
    }
    __syncthreads();

    // ===== layer 1 =====
    LOAD_AF();
    LAYER_PRE(wfA);
    PRELOAD(wmlp1_t, wfB);  // hide layer-2 weight latency under writeback+sync
    __syncthreads();
#pragma unroll
    for (int it = 0; it < 2; ++it) {
      const int i = it * 16 + li;
#pragma unroll
      for (int ol = 0; ol < 2; ++ol) {
        const int o0 = (wid * 2 + ol) * 16 + lq4;
        const float4 m2v =
            *reinterpret_cast<const float4*>(&m2p[(size_t)(i0g + i) * O + o0]);
        const float4 b1 = *reinterpret_cast<const float4*>(&m1s[o0]);
        ushort4 pk;
        pk.x = f2b(fmaxf(acc[it][ol][0] + m2v.x + b1.x, 0.f));
        pk.y = f2b(fmaxf(acc[it][ol][1] + m2v.y + b1.y, 0.f));
        pk.z = f2b(fmaxf(acc[it][ol][2] + m2v.z + b1.z, 0.f));
        pk.w = f2b(fmaxf(acc[it][ol][3] + m2v.w + b1.w, 0.f));
        *reinterpret_cast<ushort4*>(&act[i * LDK + o0]) = pk;
      }
    }
    __syncthreads();

    // ===== layer 2 =====
    LOAD_AF();
    LAYER_PRE(wfB);
    PRELOAD(wmlp2_t, wfA);
    __syncthreads();
#pragma unroll
    for (int it = 0; it < 2; ++it) {
      const int i = it * 16 + li;
#pragma unroll
      for (int ol = 0; ol < 2; ++ol) {
        const int o0 = (wid * 2 + ol) * 16 + lq4;
        ushort4 pk;
        pk.x = f2b(fmaxf(acc[it][ol][0], 0.f));
        pk.y = f2b(fmaxf(acc[it][ol][1], 0.f));
        pk.z = f2b(fmaxf(acc[it][ol][2], 0.f));
        pk.w = f2b(fmaxf(acc[it][ol][3], 0.f));
        *reinterpret_cast<ushort4*>(&act[i * LDK + o0]) = pk;
      }
    }
    __syncthreads();

    // ===== layer 3 + masked max + partial write =====
    LOAD_AF();
    LAYER_PRE(wfA);
    float* part = ws + OFF_PART + (((size_t)(b * N) + j) * 4 + ig) * O;
#pragma unroll
    for (int ol = 0; ol < 2; ++ol) {
      const int ot = wid * 2 + ol;
      float v0, v1, v2, v3;
      {
        const bool ma = maskv[li] != 0, mb = maskv[16 + li] != 0;
        v0 = fmaxf(ma ? acc[0][ol][0] : NEGV, mb ? acc[1][ol][0] : NEGV);
        v1 = fmaxf(ma ? acc[0][ol][1] : NEGV, mb ? acc[1][ol][1] : NEGV);
        v2 = fmaxf(ma ? acc[0][ol][2] : NEGV, mb ? acc[1][ol][2] : NEGV);
        v3 = fmaxf(ma ? acc[0][ol][3] : NEGV, mb ? acc[1][ol][3] : NEGV);
      }
#pragma unroll
      for (int off = 1; off < 16; off <<= 1) {
        v0 = fmaxf(v0, __shfl_xor(v0, off));
        v1 = fmaxf(v1, __shfl_xor(v1, off));
        v2 = fmaxf(v2, __shfl_xor(v2, off));
        v3 = fmaxf(v3, __shfl_xor(v3, off));
      }
      if (li == 0) {
        float4 wv = make_float4(v0, v1, v2, v3);
        *reinterpret_cast<float4*>(&part[ot * 16 + lq4]) = wv;
      }
    }
#undef PRELOAD
#undef LOAD_AF
#undef LAYER_PRE
  } else {
    // ============== tri branch (k-quarter split, wide loads) ==============
    float* A    = (float*)(smem);           // [128][8] f32
    float* wu3  = (float*)(smem + 4096);    // [8][128] f32
    float* trif = (float*)(smem + 8192);    // [32][8] f32
    float* t2j  = (float*)(smem + 9216);    // 8
    float* tgb  = (float*)(smem + 9248);    // 8
    const int blk2 = blk - 2048;
    const int kq = blk2 & 3, j = (blk2 >> 2) & 127, b = blk2 >> 9;

    const unsigned short* te1Tp =
        (const unsigned short*)(ws_c + OFF_TE1T) + ((size_t)(b * N) + j) * N * CH;
    const unsigned short* te2p =
        (const unsigned short*)(ws_c + OFF_TE2) + (size_t)b * N * N * CH;
    const unsigned short* te3p =
        (const unsigned short*)(ws_c + OFF_TE3) + ((size_t)(b * N) + j) * N * CH;
    const float* t1p = ws_c + OFF_T1 + (size_t)b * N * CH;
    const float* t3p = ws_c + OFF_T3 + (size_t)b * N * CH;

    {
      const int t4 = t * 4;
      const ushort4 tv = *reinterpret_cast<const ushort4*>(&te1Tp[t4]);
      const float4 t1v = *reinterpret_cast<const float4*>(&t1p[t4]);
      float4 av;
      av.x = b2f(tv.x) + t1v.x;
      av.y = b2f(tv.y) + t1v.y;
      av.z = b2f(tv.z) + t1v.z;
      av.w = b2f(tv.w) + t1v.w;
      *reinterpret_cast<float4*>(&A[t4]) = av;
      *reinterpret_cast<float4*>(&wu3[t4]) = *reinterpret_cast<const float4*>(&WU3[t4]);
    }
    if (t < CH) {
      t2j[t] = ws_c[OFF_T2 + ((size_t)(b * N) + j) * CH + t];
      tgb[t] = ws_c[OFF_TG + (size_t)b * CH + t];
    }
    __syncthreads();

    const int io = t & 7, kl = t >> 3;  // kl in 0..31
    const int kg = kq * 32 + kl;
    const size_t kbase = (size_t)kg * CH;
    float core[8];
#pragma unroll
    for (int c = 0; c < 8; ++c) core[c] = -3.0e38f;
#pragma unroll 4
    for (int i0 = 0; i0 < N; i0 += 8) {
      const int i = i0 + io;
      const u16x8 rv = *reinterpret_cast<const u16x8*>(&te2p[(size_t)i * N * CH + kbase]);
      const float4 a0 = *reinterpret_cast<const float4*>(&A[i * CH]);
      const float4 a1 = *reinterpret_cast<const float4*>(&A[i * CH + 4]);
      core[0] = fmaxf(core[0], a0.x + b2f(rv[0]));
      core[1] = fmaxf(core[1], a0.y + b2f(rv[1]));
      core[2] = fmaxf(core[2], a0.z + b2f(rv[2]));
      core[3] = fmaxf(core[3], a0.w + b2f(rv[3]));
      core[4] = fmaxf(core[4], a1.x + b2f(rv[4]));
      core[5] = fmaxf(core[5], a1.y + b2f(rv[5]));
      core[6] = fmaxf(core[6], a1.z + b2f(rv[6]));
      core[7] = fmaxf(core[7], a1.w + b2f(rv[7]));
    }
#pragma unroll
    for (int c = 0; c < 8; ++c) {
      core[c] = fmaxf(core[c], __shfl_xor(core[c], 1));
      core[c] = fmaxf(core[c], __shfl_xor(core[c], 2));
      core[c] = fmaxf(core[c], __shfl_xor(core[c], 4));
    }
    // lane io writes channel io (static select to avoid scratch)
    float cv = core[0];
#pragma unroll
    for (int c = 1; c < 8; ++c) cv = (io == c) ? core[c] : cv;
    trif[kl * CH + io] =
        cv + t2j[io] + t3p[kbase + io] + b2f(te3p[kbase + io]) + tgb[io];
    __syncthreads();

    float* outp = out_tri + ((size_t)(b * N) + j) * N * O;
    for (int q = 0; q < 16; ++q) {
      const int idx = q * 256 + t;
      const int klr = idx >> 7, o = idx & 127;
      float acc2 = 0.f;
#pragma unroll
      for (int c = 0; c < CH; ++c) acc2 += trif[klr * CH + c] * wu3[c * O + o];
      outp[(size_t)(kq * 32 + klr) * O + o] = acc2;
    }
  }
}

// ---------------------------------------------------------------------------
// Kernel C: finalize msgs + ret
// ---------------------------------------------------------------------------
__global__ __launch_bounds__(256) void k_fin(
    const float* __restrict__ WU2, const float* __restrict__ ws,
    float* __restrict__ out_ret, float* __restrict__ out_msgs) {
  const int blk = blockIdx.x;
  const int b = blk >> 7, j = blk & 127;
  const int t = threadIdx.x;
  __shared__ float msgsrow[O];
  __shared__ float red[2][O];

  const float* part = ws + OFF_PART + ((size_t)(b * N) + j) * 4 * O;
  if (t < O) {
    const float m = fmaxf(fmaxf(part[t], part[O + t]),
                          fmaxf(part[2 * O + t], part[3 * O + t]));
    msgsrow[t] = m;
    out_msgs[((size_t)(b * N) + j) * O + t] = m;
  }
  __syncthreads();

  const int o = t & 127, h = t >> 7;
  float acc = 0.f;
#pragma unroll 8
  for (int p = h * 64; p < h * 64 + 64; ++p)
    acc += msgsrow[p] * WU2[(size_t)p * O + o];
  red[h][o] = acc;
  __syncthreads();
  if (t < O) {
    out_ret[((size_t)(b * N) + j) * O + t] =
        ws[OFF_ZU1 + ((size_t)(b * N) + j) * O + t] + red[0][t] + red[1][t];
  }
}

// ---------------------------------------------------------------------------
extern "C" void kernel_launch(void* const* d_in, const int* in_sizes, int n_in,
                              void* d_out, int out_size, void* d_ws,
                              size_t ws_size, hipStream_t stream) {
  const float* z    = (const float*)d_in[0];
  const float* e    = (const float*)d_in[1];
  const float* g    = (const float*)d_in[2];
  const void*  mmsk = d_in[4];
  const float* Wt1  = (const float*)d_in[5];
  const float* Wt2  = (const float*)d_in[6];
  const float* Wt3  = (const float*)d_in[7];
  const float* Wte1 = (const float*)d_in[8];
  const float* Wte2 = (const float*)d_in[9];
  const float* Wte3 = (const float*)d_in[10];
  const float* Wtg  = (const float*)d_in[11];
  const float* Wm1  = (const float*)d_in[12];
  const float* Wm2  = (const float*)d_in[13];
  const float* Wme  = (const float*)d_in[14];
  const float* Wmg  = (const float*)d_in[15];
  const float* Wmlp1= (const float*)d_in[16];
  const float* Wmlp2= (const float*)d_in[17];
  const float* WU1  = (const float*)d_in[18];
  const float* WU2  = (const float*)d_in[19];
  const float* WU3  = (const float*)d_in[20];

  float* ws = (float*)d_ws;
  float* out_ret  = (float*)d_out;
  float* out_msgs = out_ret + (size_t)B * N * O;
  float* out_tri  = out_msgs + (size_t)B * N * O;

  dim3 blk(256);
  k_prep<<<1027, blk, 0, stream>>>(z, g, e, Wt1, Wt2, Wt3, Wtg, Wm1, Wm2, Wmg,
                                   WU1, Wte1, Wte2, Wte3, Wme, Wmlp1, Wmlp2, ws);
  k_main<<<4096, blk, 0, stream>>>(e, mmsk, WU3, ws, ws, out_tri);
  k_fin<<<B * N, blk, 0, stream>>>(WU2, ws, out_ret, out_msgs);
}

// Round 8
// 69.392 us; speedup vs baseline: 1.7417x; 1.2043x over previous
//
#include <hip/hip_runtime.h>
#include <hip/hip_bf16.h>
#include <cstdint>
#include <cstddef>

namespace {

constexpr int B = 4, N = 128, C = 256, E = 128, O = 128, CH = 8;
constexpr float NEGV = -1.0e9f;

// ---- workspace layout (in float units) ----
constexpr size_t SZ_TE_F  = (size_t)B * N * N * CH / 2;   // bf16 tensors
constexpr size_t OFF_TE1T = 0;                             // bf16 [b][j][i][c]
constexpr size_t OFF_TE2  = OFF_TE1T + SZ_TE_F;            // bf16 [b][i][k][c]
constexpr size_t OFF_TE3  = OFF_TE2 + SZ_TE_F;             // bf16 [b][j][k][c]
constexpr size_t OFF_M1   = OFF_TE3 + SZ_TE_F;             // f32 m1+mg [b][n][o]
constexpr size_t OFF_M2   = OFF_M1 + (size_t)B * N * O;
constexpr size_t OFF_ZU1  = OFF_M2 + (size_t)B * N * O;    // f32 [b][n][o]
constexpr size_t OFF_T1   = OFF_ZU1 + (size_t)B * N * O;   // f32 [b][n][c]
constexpr size_t OFF_T2   = OFF_T1 + (size_t)B * N * CH;
constexpr size_t OFF_T3   = OFF_T2 + (size_t)B * N * CH;
constexpr size_t OFF_TG   = OFF_T3 + (size_t)B * N * CH;   // f32 [b][c]
constexpr size_t OFF_WT   = OFF_TG + (size_t)B * CH;       // 3 x bf16[O][E]
constexpr size_t OFF_PART = OFF_WT + (size_t)3 * O * E / 2;  // f32 [b][j][4][o]

typedef __attribute__((ext_vector_type(4))) float f32x4;
typedef __attribute__((ext_vector_type(8))) short bf16x8;
typedef __attribute__((ext_vector_type(8))) unsigned short u16x8;

__device__ __forceinline__ unsigned short f2b(float f) {
  unsigned u = __float_as_uint(f);
  u = (u + 0x7fffu + ((u >> 16) & 1u)) >> 16;
  return (unsigned short)u;
}
__device__ __forceinline__ float b2f(unsigned short u) {
  return __uint_as_float((unsigned)u << 16);
}

} // namespace

// ---------------------------------------------------------------------------
// Kernel A (prep): fused te-MFMA [0,512) + pre [512,1024) + wprep [1024,1027)
// ---------------------------------------------------------------------------
__global__ __launch_bounds__(256) void k_prep(
    const float* __restrict__ z, const float* __restrict__ g,
    const float* __restrict__ e,
    const float* __restrict__ Wt1, const float* __restrict__ Wt2,
    const float* __restrict__ Wt3, const float* __restrict__ Wtg,
    const float* __restrict__ Wm1, const float* __restrict__ Wm2,
    const float* __restrict__ Wmg, const float* __restrict__ WU1,
    const float* __restrict__ Wte1, const float* __restrict__ Wte2,
    const float* __restrict__ Wte3,
    const float* __restrict__ Wme, const float* __restrict__ Wmlp1,
    const float* __restrict__ Wmlp2, float* __restrict__ ws) {
  __shared__ __align__(16) char smem[25600];
  const int blk = blockIdx.x;
  const int t = threadIdx.x;

  if (blk < 512) {
    // ============ te branch (MFMA, plain [r][136] LDS) ============
    unsigned short* wpack = (unsigned short*)(smem);            // [32][136]
    unsigned short* ebuf  = (unsigned short*)(smem + 8704);     // [32][136]
    unsigned short* outl  = (unsigned short*)(smem + 17408);    // [128][32]
    unsigned short* te1T = (unsigned short*)(ws + OFF_TE1T);
    unsigned short* te2  = (unsigned short*)(ws + OFF_TE2);
    unsigned short* te3  = (unsigned short*)(ws + OFF_TE3);
    const int b = blk >> 7, i = blk & 127;

    for (int x = t; x < 3072; x += 256) {
      const int m = x >> 10, rem = x & 1023, k = rem >> 3, c = rem & 7;
      const float* W = (m == 0) ? Wte1 : ((m == 1) ? Wte2 : Wte3);
      const int row = m * 8 + c;
      wpack[row * 136 + k] = f2b(W[rem]);
    }
    for (int x = t; x < 1024; x += 256) {
      const int row = 24 + (x >> 7), col = x & 127;
      wpack[row * 136 + col] = 0;
    }

    const float* erow = e + ((size_t)(b * N) + i) * N * E;
    const int lane = t & 63, wid = t >> 6;
    const int li = lane & 15, lk8 = (lane >> 4) * 8, lq4 = (lane >> 4) * 4;
    const int jt = wid & 1, ct = wid >> 1;

    for (int j0 = 0; j0 < N; j0 += 32) {
      __syncthreads();
      for (int x = t; x < 1024; x += 256) {
        const int r = x >> 5, seg = x & 31;
        const float4 v = *reinterpret_cast<const float4*>(
            &erow[(size_t)(j0 + r) * E + seg * 4]);
        ushort4 pk;
        pk.x = f2b(v.x); pk.y = f2b(v.y); pk.z = f2b(v.z); pk.w = f2b(v.w);
        *reinterpret_cast<ushort4*>(&ebuf[r * 136 + seg * 4]) = pk;
      }
      __syncthreads();
      f32x4 acc = {0.f, 0.f, 0.f, 0.f};
#pragma unroll
      for (int kt = 0; kt < 4; ++kt) {
        const int rw = ct * 16 + li, ra = jt * 16 + li;
        const bf16x8 wf = *reinterpret_cast<const bf16x8*>(
            &wpack[rw * 136 + kt * 32 + lk8]);
        const bf16x8 af = *reinterpret_cast<const bf16x8*>(
            &ebuf[ra * 136 + kt * 32 + lk8]);
        acc = __builtin_amdgcn_mfma_f32_16x16x32_bf16(wf, af, acc, 0, 0, 0);
      }
      const int c0 = ct * 16 + lq4;
      if (c0 < 24) {
        ushort4 pk;
        pk.x = f2b(acc[0]); pk.y = f2b(acc[1]);
        pk.z = f2b(acc[2]); pk.w = f2b(acc[3]);
        *reinterpret_cast<ushort4*>(&outl[(j0 + jt * 16 + li) * 32 + c0]) = pk;
      }
    }
    __syncthreads();
    for (int x = t; x < 384; x += 256) {
      const int m = x >> 7, j = x & 127;
      const u16x8 v = *reinterpret_cast<const u16x8*>(&outl[j * 32 + m * 8]);
      if (m == 0)
        *reinterpret_cast<u16x8*>(&te1T[(((size_t)(b * N) + j) * N + i) * CH]) = v;
      else if (m == 1)
        *reinterpret_cast<u16x8*>(&te2[(((size_t)(b * N) + i) * N + j) * CH]) = v;
      else
        *reinterpret_cast<u16x8*>(&te3[(((size_t)(b * N) + i) * N + j) * CH]) = v;
    }
  } else if (blk < 1024) {
    // ===================== pre branch =====================
    float* zrow = (float*)(smem);
    float* grow = (float*)(smem + 1024);
    const int bn = blk - 512;
    const int b = bn >> 7, n = bn & 127;

    for (int k = t; k < C; k += 256) zrow[k] = z[((size_t)(b * N) + n) * C + k];
    if (t < C / 2) grow[t] = g[(size_t)b * (C / 2) + t];
    __syncthreads();

    {
      const int o = t & 127;
      const float* W = (t < 128) ? Wm1 : Wm2;
      float acc = 0.f;
#pragma unroll 8
      for (int k = 0; k < C; ++k) acc += zrow[k] * W[(size_t)k * O + o];
      if (t < 128) {
        float mgacc = 0.f;
        for (int k = 0; k < C / 2; ++k) mgacc += grow[k] * Wmg[(size_t)k * O + o];
        acc += mgacc;
        ws[OFF_M1 + ((size_t)(b * N) + n) * O + o] = acc;
      } else {
        ws[OFF_M2 + ((size_t)(b * N) + n) * O + o] = acc;
      }
    }
    if (t < 128) {
      float acc = 0.f;
#pragma unroll 8
      for (int k = 0; k < C; ++k) acc += zrow[k] * WU1[(size_t)k * O + t];
      ws[OFF_ZU1 + ((size_t)(b * N) + n) * O + t] = acc;
    } else if (t < 152) {
      const int idx = t - 128;
      const int which = idx >> 3, c = idx & 7;
      const float* W = (which == 0) ? Wt1 : ((which == 1) ? Wt2 : Wt3);
      float acc = 0.f;
      for (int k = 0; k < C; ++k) acc += zrow[k] * W[(size_t)k * CH + c];
      const size_t off = (which == 0) ? OFF_T1 : ((which == 1) ? OFF_T2 : OFF_T3);
      ws[off + ((size_t)(b * N) + n) * CH + c] = acc;
    }
    if (n == 0 && t >= 152 && t < 160) {
      const int c = t - 152;
      float acc = 0.f;
      for (int k = 0; k < C / 2; ++k) acc += grow[k] * Wtg[(size_t)k * CH + c];
      ws[OFF_TG + (size_t)b * CH + c] = acc;
    }
  } else {
    // ===================== wprep branch =====================
    const int which = blk - 1024;
    const float* W = (which == 0) ? Wme : ((which == 1) ? Wmlp1 : Wmlp2);
    unsigned short* dst = (unsigned short*)(ws + OFF_WT) + (size_t)which * O * E;
    for (int x = t; x < O * E; x += 256) {
      const int o = x >> 7, k = x & 127;
      dst[x] = f2b(W[(size_t)k * O + o]);
    }
  }
}

// ---------------------------------------------------------------------------
// Kernel B (main): fused msgs (2-j tiles) [0,1024) + tri (4-j, k-quarter)
// [1024,1536)
// ---------------------------------------------------------------------------
__global__ __launch_bounds__(256) void k_main(
    const float* __restrict__ e, const void* __restrict__ msk,
    const float* __restrict__ WU3, const float* __restrict__ ws_c,
    float* __restrict__ ws, float* __restrict__ out_tri) {
  __shared__ __align__(16) char smem[24768];
  const int blk = blockIdx.x;
  const int t = threadIdx.x;

  if (blk < 1024) {
    // ============== msgs branch: (b, j0..j0+1, ig) ==============
    unsigned short* act0 = (unsigned short*)(smem);            // [32][136]
    unsigned short* act1 = (unsigned short*)(smem + 8704);     // [32][136]
    float* m1s0 = (float*)(smem + 17408);                      // 128 f32
    float* m1s1 = (float*)(smem + 17920);                      // 128 f32
    int* maskv0 = (int*)(smem + 18432);                        // 32
    int* maskv1 = (int*)(smem + 18560);                        // 32
    int* fmtp   = (int*)(smem + 18688);
    const int ig = blk & 3, jp = (blk >> 2) & 63, b = blk >> 8;
    const int j0 = jp * 2;
    const int i0g = ig * 32;
    constexpr int LDK = 136;

    const int lane = t & 63, wid = t >> 6;
    const int li = lane & 15;
    const int lk8 = (lane >> 4) * 8;
    const int lq4 = (lane >> 4) * 4;

    const unsigned short* wts = (const unsigned short*)(ws_c + OFF_WT);
    const unsigned short* wme_t   = wts;
    const unsigned short* wmlp1_t = wts + (size_t)O * E;
    const unsigned short* wmlp2_t = wts + (size_t)2 * O * E;
    const float* m2p = ws_c + OFF_M2 + (size_t)b * N * O;

    f32x4 acc0[2][2], acc1[2][2];
    bf16x8 af0[2][4], af1[2][4];

    if (t < 64) {
      const unsigned w = ((const unsigned*)msk)[t];
      const float f = __uint_as_float(w);
      const unsigned long long bad_int = __ballot(w > 1u);
      const unsigned long long bad_flt = __ballot(!(f == 0.f || f == 1.f));
      if (t == 0) *fmtp = (bad_int == 0ull) ? 0 : ((bad_flt == 0ull) ? 2 : 1);
    }
    __syncthreads();
    const int fmt = *fmtp;
    if (t < 64) {
      const int jj = t >> 5, tt = t & 31;
      const size_t idx = ((size_t)(b * N) + i0g + tt) * N + j0 + jj;
      int mv;
      if (fmt == 0)      mv = ((const int*)msk)[idx] != 0;
      else if (fmt == 1) mv = ((const unsigned char*)msk)[idx] != 0;
      else               mv = ((const float*)msk)[idx] != 0.f;
      (jj ? maskv1 : maskv0)[tt] = mv;
    }
    if (t < 128) m1s0[t] = ws_c[OFF_M1 + ((size_t)(b * N) + j0) * O + t];
    else m1s1[t - 128] = ws_c[OFF_M1 + ((size_t)(b * N) + j0 + 1) * O + (t - 128)];
    __syncthreads();

    // stage masked e rows for both j
#pragma unroll
    for (int jj = 0; jj < 2; ++jj) {
      unsigned short* actp = jj ? act1 : act0;
      const int* mv = jj ? maskv1 : maskv0;
      const float* ep = e + (((size_t)(b * N) + i0g) * N + j0 + jj) * E;
      for (int x = t; x < 32 * 32; x += 256) {
        const int row = x >> 5, seg = x & 31;
        const float4 v =
            *reinterpret_cast<const float4*>(&ep[(size_t)row * N * E + seg * 4]);
        ushort4 pk;
        if (mv[row]) {
          pk.x = f2b(v.x); pk.y = f2b(v.y); pk.z = f2b(v.z); pk.w = f2b(v.w);
        } else {
          pk.x = pk.y = pk.z = pk.w = 0;
        }
        *reinterpret_cast<ushort4*>(&actp[row * LDK + seg * 4]) = pk;
      }
    }
    __syncthreads();

#define LOAD_AF2()                                                        \
  _Pragma("unroll") for (int it = 0; it < 2; ++it)                        \
      _Pragma("unroll") for (int kt = 0; kt < 4; ++kt) {                  \
        const int r_ = it * 16 + li;                                      \
        af0[it][kt] = *reinterpret_cast<const bf16x8*>(                   \
            &act0[r_ * LDK + kt * 32 + lk8]);                             \
        af1[it][kt] = *reinterpret_cast<const bf16x8*>(                   \
            &act1[r_ * LDK + kt * 32 + lk8]);                             \
      }

#define LAYER2(WT)                                                        \
  _Pragma("unroll") for (int it = 0; it < 2; ++it)                        \
      _Pragma("unroll") for (int ol = 0; ol < 2; ++ol) {                  \
        acc0[it][ol] = (f32x4){0.f, 0.f, 0.f, 0.f};                       \
        acc1[it][ol] = (f32x4){0.f, 0.f, 0.f, 0.f};                       \
      }                                                                   \
  _Pragma("unroll") for (int ol = 0; ol < 2; ++ol) {                      \
    _Pragma("unroll") for (int kt = 0; kt < 4; ++kt) {                    \
      const bf16x8 wf = *reinterpret_cast<const bf16x8*>(                 \
          &(WT)[(size_t)((wid * 2 + ol) * 16 + li) * E + kt * 32 + lk8]); \
      acc0[0][ol] = __builtin_amdgcn_mfma_f32_16x16x32_bf16(              \
          wf, af0[0][kt], acc0[0][ol], 0, 0, 0);                          \
      acc0[1][ol] = __builtin_amdgcn_mfma_f32_16x16x32_bf16(              \
          wf, af0[1][kt], acc0[1][ol], 0, 0, 0);                          \
      acc1[0][ol] = __builtin_amdgcn_mfma_f32_16x16x32_bf16(              \
          wf, af1[0][kt], acc1[0][ol], 0, 0, 0);                          \
      acc1[1][ol] = __builtin_amdgcn_mfma_f32_16x16x32_bf16(              \
          wf, af1[1][kt], acc1[1][ol], 0, 0, 0);                          \
    }                                                                     \
  }

    // ===== layer 1: me + m1' + m2, relu =====
    LOAD_AF2();
    LAYER2(wme_t);
    __syncthreads();
#pragma unroll
    for (int it = 0; it < 2; ++it) {
      const int i = it * 16 + li;
#pragma unroll
      for (int ol = 0; ol < 2; ++ol) {
        const int o0 = (wid * 2 + ol) * 16 + lq4;
        const float4 m2v =
            *reinterpret_cast<const float4*>(&m2p[(size_t)(i0g + i) * O + o0]);
        ushort4 p0, p1;
        p0.x = f2b(fmaxf(acc0[it][ol][0] + m2v.x + m1s0[o0 + 0], 0.f));
        p0.y = f2b(fmaxf(acc0[it][ol][1] + m2v.y + m1s0[o0 + 1], 0.f));
        p0.z = f2b(fmaxf(acc0[it][ol][2] + m2v.z + m1s0[o0 + 2], 0.f));
        p0.w = f2b(fmaxf(acc0[it][ol][3] + m2v.w + m1s0[o0 + 3], 0.f));
        p1.x = f2b(fmaxf(acc1[it][ol][0] + m2v.x + m1s1[o0 + 0], 0.f));
        p1.y = f2b(fmaxf(acc1[it][ol][1] + m2v.y + m1s1[o0 + 1], 0.f));
        p1.z = f2b(fmaxf(acc1[it][ol][2] + m2v.z + m1s1[o0 + 2], 0.f));
        p1.w = f2b(fmaxf(acc1[it][ol][3] + m2v.w + m1s1[o0 + 3], 0.f));
        *reinterpret_cast<ushort4*>(&act0[i * LDK + o0]) = p0;
        *reinterpret_cast<ushort4*>(&act1[i * LDK + o0]) = p1;
      }
    }
    __syncthreads();

    // ===== layer 2: @Wmlp1, relu =====
    LOAD_AF2();
    LAYER2(wmlp1_t);
    __syncthreads();
#pragma unroll
    for (int it = 0; it < 2; ++it) {
      const int i = it * 16 + li;
#pragma unroll
      for (int ol = 0; ol < 2; ++ol) {
        const int o0 = (wid * 2 + ol) * 16 + lq4;
        ushort4 p0, p1;
        p0.x = f2b(fmaxf(acc0[it][ol][0], 0.f));
        p0.y = f2b(fmaxf(acc0[it][ol][1], 0.f));
        p0.z = f2b(fmaxf(acc0[it][ol][2], 0.f));
        p0.w = f2b(fmaxf(acc0[it][ol][3], 0.f));
        p1.x = f2b(fmaxf(acc1[it][ol][0], 0.f));
        p1.y = f2b(fmaxf(acc1[it][ol][1], 0.f));
        p1.z = f2b(fmaxf(acc1[it][ol][2], 0.f));
        p1.w = f2b(fmaxf(acc1[it][ol][3], 0.f));
        *reinterpret_cast<ushort4*>(&act0[i * LDK + o0]) = p0;
        *reinterpret_cast<ushort4*>(&act1[i * LDK + o0]) = p1;
      }
    }
    __syncthreads();

    // ===== layer 3: @Wmlp2, mask -> NEG, max over 32 rows, 2 partials =====
    LOAD_AF2();
    LAYER2(wmlp2_t);
    float* part0 = ws + OFF_PART + (((size_t)(b * N) + j0) * 4 + ig) * O;
    float* part1 = ws + OFF_PART + (((size_t)(b * N) + j0 + 1) * 4 + ig) * O;
#pragma unroll
    for (int jj = 0; jj < 2; ++jj) {
      const int* mv = jj ? maskv1 : maskv0;
      const bool ma = mv[li] != 0, mb = mv[16 + li] != 0;
      float* part = jj ? part1 : part0;
#pragma unroll
      for (int ol = 0; ol < 2; ++ol) {
        const int ot = wid * 2 + ol;
        float v0, v1, v2, v3;
        {
          const f32x4 aA = jj ? acc1[0][ol] : acc0[0][ol];
          const f32x4 aB = jj ? acc1[1][ol] : acc0[1][ol];
          v0 = fmaxf(ma ? aA[0] : NEGV, mb ? aB[0] : NEGV);
          v1 = fmaxf(ma ? aA[1] : NEGV, mb ? aB[1] : NEGV);
          v2 = fmaxf(ma ? aA[2] : NEGV, mb ? aB[2] : NEGV);
          v3 = fmaxf(ma ? aA[3] : NEGV, mb ? aB[3] : NEGV);
        }
#pragma unroll
        for (int off = 1; off < 16; off <<= 1) {
          v0 = fmaxf(v0, __shfl_xor(v0, off));
          v1 = fmaxf(v1, __shfl_xor(v1, off));
          v2 = fmaxf(v2, __shfl_xor(v2, off));
          v3 = fmaxf(v3, __shfl_xor(v3, off));
        }
        if (li == 0) {
          float4 wv = make_float4(v0, v1, v2, v3);
          *reinterpret_cast<float4*>(&part[ot * 16 + lq4]) = wv;
        }
      }
    }
#undef LOAD_AF2
#undef LAYER2
  } else {
    // ============== tri branch: (b, kq, j0..j0+3) ==============
    float* A4   = (float*)(smem);            // [4][128][8]
    float* wu3  = (float*)(smem + 16384);    // [8][128]
    float* trif = (float*)(smem + 20480);    // [4][32][8]
    float* t2j4 = (float*)(smem + 24576);    // [4][8]
    float* tgb  = (float*)(smem + 24704);    // [8]
    const int blk2 = blk - 1024;
    const int kq = blk2 & 3, jt = (blk2 >> 2) & 31, b = blk2 >> 7;
    const int j0 = jt * 4;

    const unsigned short* te1T = (const unsigned short*)(ws_c + OFF_TE1T);
    const unsigned short* te2p =
        (const unsigned short*)(ws_c + OFF_TE2) + (size_t)b * N * N * CH;
    const unsigned short* te3p = (const unsigned short*)(ws_c + OFF_TE3);
    const float* t1p = ws_c + OFF_T1 + (size_t)b * N * CH;
    const float* t3p = ws_c + OFF_T3 + (size_t)b * N * CH;

    {
      const int t4 = t * 4;
      const float4 t1v = *reinterpret_cast<const float4*>(&t1p[t4]);
#pragma unroll
      for (int jj = 0; jj < 4; ++jj) {
        const ushort4 tv = *reinterpret_cast<const ushort4*>(
            &te1T[((size_t)(b * N) + j0 + jj) * N * CH + t4]);
        float4 av;
        av.x = b2f(tv.x) + t1v.x;
        av.y = b2f(tv.y) + t1v.y;
        av.z = b2f(tv.z) + t1v.z;
        av.w = b2f(tv.w) + t1v.w;
        *reinterpret_cast<float4*>(&A4[jj * 1024 + t4]) = av;
      }
      *reinterpret_cast<float4*>(&wu3[t4]) =
          *reinterpret_cast<const float4*>(&WU3[t4]);
    }
    if (t < 32)
      t2j4[t] = ws_c[OFF_T2 + ((size_t)(b * N) + j0 + (t >> 3)) * CH + (t & 7)];
    if (t < 8) tgb[t] = ws_c[OFF_TG + (size_t)b * CH + t];
    __syncthreads();

    const int io = t & 7, kl = t >> 3;  // kl 0..31
    const int kg = kq * 32 + kl;
    const size_t kbase = (size_t)kg * CH;
    float core[4][8];
#pragma unroll
    for (int jj = 0; jj < 4; ++jj)
#pragma unroll
      for (int c = 0; c < 8; ++c) core[jj][c] = -3.0e38f;

#pragma unroll 2
    for (int i0 = 0; i0 < N; i0 += 8) {
      const int i = i0 + io;
      const u16x8 rv =
          *reinterpret_cast<const u16x8*>(&te2p[(size_t)i * N * CH + kbase]);
      float r[8];
#pragma unroll
      for (int c = 0; c < 8; ++c) r[c] = b2f(rv[c]);
#pragma unroll
      for (int jj = 0; jj < 4; ++jj) {
        const float4 a0 = *reinterpret_cast<const float4*>(&A4[jj * 1024 + i * 8]);
        const float4 a1 = *reinterpret_cast<const float4*>(&A4[jj * 1024 + i * 8 + 4]);
        core[jj][0] = fmaxf(core[jj][0], a0.x + r[0]);
        core[jj][1] = fmaxf(core[jj][1], a0.y + r[1]);
        core[jj][2] = fmaxf(core[jj][2], a0.z + r[2]);
        core[jj][3] = fmaxf(core[jj][3], a0.w + r[3]);
        core[jj][4] = fmaxf(core[jj][4], a1.x + r[4]);
        core[jj][5] = fmaxf(core[jj][5], a1.y + r[5]);
        core[jj][6] = fmaxf(core[jj][6], a1.z + r[6]);
        core[jj][7] = fmaxf(core[jj][7], a1.w + r[7]);
      }
    }
#pragma unroll
    for (int jj = 0; jj < 4; ++jj)
#pragma unroll
      for (int c = 0; c < 8; ++c) {
        core[jj][c] = fmaxf(core[jj][c], __shfl_xor(core[jj][c], 1));
        core[jj][c] = fmaxf(core[jj][c], __shfl_xor(core[jj][c], 2));
        core[jj][c] = fmaxf(core[jj][c], __shfl_xor(core[jj][c], 4));
      }
    // lane io finalizes channel c = io for each jj
#pragma unroll
    for (int jj = 0; jj < 4; ++jj) {
      float cv = core[jj][0];
#pragma unroll
      for (int c = 1; c < 8; ++c) cv = (io == c) ? core[jj][c] : cv;
      const unsigned short t3e =
          te3p[((size_t)(b * N) + j0 + jj) * N * CH + kbase + io];
      trif[jj * 256 + kl * 8 + io] =
          cv + t2j4[jj * 8 + io] + t3p[kbase + io] + b2f(t3e) + tgb[io];
    }
    __syncthreads();

    // epilogue: out[jj, k, o] = trif[row] . wu3[:, o]
    const int o = t & 127, rh = t >> 7;
    float wcol[8];
#pragma unroll
    for (int c = 0; c < 8; ++c) wcol[c] = wu3[c * 128 + o];
#pragma unroll 4
    for (int q = 0; q < 64; ++q) {
      const int row = q * 2 + rh;  // 0..127 = jj*32 + klr
      const int jj = row >> 5, klr = row & 31;
      const float4 f0 = *reinterpret_cast<const float4*>(&trif[row * 8]);
      const float4 f1 = *reinterpret_cast<const float4*>(&trif[row * 8 + 4]);
      float acc2 = f0.x * wcol[0] + f0.y * wcol[1] + f0.z * wcol[2] +
                   f0.w * wcol[3] + f1.x * wcol[4] + f1.y * wcol[5] +
                   f1.z * wcol[6] + f1.w * wcol[7];
      out_tri[((size_t)(b * N) + j0 + jj) * N * O + (size_t)(kq * 32 + klr) * O + o] = acc2;
    }
  }
}

// ---------------------------------------------------------------------------
// Kernel C: finalize msgs + ret
// ---------------------------------------------------------------------------
__global__ __launch_bounds__(256) void k_fin(
    const float* __restrict__ WU2, const float* __restrict__ ws,
    float* __restrict__ out_ret, float* __restrict__ out_msgs) {
  const int blk = blockIdx.x;
  const int b = blk >> 7, j = blk & 127;
  const int t = threadIdx.x;
  __shared__ float msgsrow[O];
  __shared__ float red[2][O];

  const float* part = ws + OFF_PART + ((size_t)(b * N) + j) * 4 * O;
  if (t < O) {
    const float m = fmaxf(fmaxf(part[t], part[O + t]),
                          fmaxf(part[2 * O + t], part[3 * O + t]));
    msgsrow[t] = m;
    out_msgs[((size_t)(b * N) + j) * O + t] = m;
  }
  __syncthreads();

  const int o = t & 127, h = t >> 7;
  float acc = 0.f;
#pragma unroll 8
  for (int p = h * 64; p < h * 64 + 64; ++p)
    acc += msgsrow[p] * WU2[(size_t)p * O + o];
  red[h][o] = acc;
  __syncthreads();
  if (t < O) {
    out_ret[((size_t)(b * N) + j) * O + t] =
        ws[OFF_ZU1 + ((size_t)(b * N) + j) * O + t] + red[0][t] + red[1][t];
  }
}

// ---------------------------------------------------------------------------
extern "C" void kernel_launch(void* const* d_in, const int* in_sizes, int n_in,
                              void* d_out, int out_size, void* d_ws,
                              size_t ws_size, hipStream_t stream) {
  const float* z    = (const float*)d_in[0];
  const float* e    = (const float*)d_in[1];
  const float* g    = (const float*)d_in[2];
  const void*  mmsk = d_in[4];
  const float* Wt1  = (const float*)d_in[5];
  const float* Wt2  = (const float*)d_in[6];
  const float* Wt3  = (const float*)d_in[7];
  const float* Wte1 = (const float*)d_in[8];
  const float* Wte2 = (const float*)d_in[9];
  const float* Wte3 = (const float*)d_in[10];
  const float* Wtg  = (const float*)d_in[11];
  const float* Wm1  = (const float*)d_in[12];
  const float* Wm2  = (const float*)d_in[13];
  const float* Wme  = (const float*)d_in[14];
  const float* Wmg  = (const float*)d_in[15];
  const float* Wmlp1= (const float*)d_in[16];
  const float* Wmlp2= (const float*)d_in[17];
  const float* WU1  = (const float*)d_in[18];
  const float* WU2  = (const float*)d_in[19];
  const float* WU3  = (const float*)d_in[20];

  float* ws = (float*)d_ws;
  float* out_ret  = (float*)d_out;
  float* out_msgs = out_ret + (size_t)B * N * O;
  float* out_tri  = out_msgs + (size_t)B * N * O;

  dim3 blk(256);
  k_prep<<<1027, blk, 0, stream>>>(z, g, e, Wt1, Wt2, Wt3, Wtg, Wm1, Wm2, Wmg,
                                   WU1, Wte1, Wte2, Wte3, Wme, Wmlp1, Wmlp2, ws);
  k_main<<<1536, blk, 0, stream>>>(e, mmsk, WU3, ws, ws, out_tri);
  k_fin<<<B * N, blk, 0, stream>>>(WU2, ws, out_ret, out_msgs);
}

// Round 9
// 63.960 us; speedup vs baseline: 1.8896x; 1.0849x over previous
//
#include <hip/hip_runtime.h>
#include <hip/hip_bf16.h>
#include <cstdint>
#include <cstddef>

namespace {

constexpr int B = 4, N = 128, C = 256, E = 128, O = 128, CH = 8;
constexpr float NEGV = -1.0e9f;

// ---- workspace layout (in float units) ----
constexpr size_t SZ_TE_F  = (size_t)B * N * N * CH / 2;   // bf16 tensors
constexpr size_t OFF_TE1T = 0;                             // bf16 [b][j][i][c]
constexpr size_t OFF_TE2  = OFF_TE1T + SZ_TE_F;            // bf16 [b][i][k][c]
constexpr size_t OFF_TE3  = OFF_TE2 + SZ_TE_F;             // bf16 [b][j][k][c]
constexpr size_t OFF_M1   = OFF_TE3 + SZ_TE_F;             // f32 m1+mg [b][n][o]
constexpr size_t OFF_M2   = OFF_M1 + (size_t)B * N * O;
constexpr size_t OFF_ZU1  = OFF_M2 + (size_t)B * N * O;    // f32 [b][n][o]
constexpr size_t OFF_T1   = OFF_ZU1 + (size_t)B * N * O;   // f32 [b][n][c]
constexpr size_t OFF_T2   = OFF_T1 + (size_t)B * N * CH;
constexpr size_t OFF_T3   = OFF_T2 + (size_t)B * N * CH;
constexpr size_t OFF_TG   = OFF_T3 + (size_t)B * N * CH;   // f32 [b][c]
constexpr size_t OFF_WT   = OFF_TG + (size_t)B * CH;       // 3 x bf16[O][E]
constexpr size_t OFF_PART = OFF_WT + (size_t)3 * O * E / 2;  // f32 [b][j][4][o]

typedef __attribute__((ext_vector_type(4))) float f32x4;
typedef __attribute__((ext_vector_type(8))) short bf16x8;
typedef __attribute__((ext_vector_type(8))) unsigned short u16x8;

__device__ __forceinline__ unsigned short f2b(float f) {
  unsigned u = __float_as_uint(f);
  u = (u + 0x7fffu + ((u >> 16) & 1u)) >> 16;
  return (unsigned short)u;
}
__device__ __forceinline__ float b2f(unsigned short u) {
  return __uint_as_float((unsigned)u << 16);
}

} // namespace

// ---------------------------------------------------------------------------
// Kernel A (prep): fused te-MFMA [0,512) + pre [512,1024) + wprep [1024,1027)
// (unchanged from round 8)
// ---------------------------------------------------------------------------
__global__ __launch_bounds__(256) void k_prep(
    const float* __restrict__ z, const float* __restrict__ g,
    const float* __restrict__ e,
    const float* __restrict__ Wt1, const float* __restrict__ Wt2,
    const float* __restrict__ Wt3, const float* __restrict__ Wtg,
    const float* __restrict__ Wm1, const float* __restrict__ Wm2,
    const float* __restrict__ Wmg, const float* __restrict__ WU1,
    const float* __restrict__ Wte1, const float* __restrict__ Wte2,
    const float* __restrict__ Wte3,
    const float* __restrict__ Wme, const float* __restrict__ Wmlp1,
    const float* __restrict__ Wmlp2, float* __restrict__ ws) {
  __shared__ __align__(16) char smem[25600];
  const int blk = blockIdx.x;
  const int t = threadIdx.x;

  if (blk < 512) {
    unsigned short* wpack = (unsigned short*)(smem);            // [32][136]
    unsigned short* ebuf  = (unsigned short*)(smem + 8704);     // [32][136]
    unsigned short* outl  = (unsigned short*)(smem + 17408);    // [128][32]
    unsigned short* te1T = (unsigned short*)(ws + OFF_TE1T);
    unsigned short* te2  = (unsigned short*)(ws + OFF_TE2);
    unsigned short* te3  = (unsigned short*)(ws + OFF_TE3);
    const int b = blk >> 7, i = blk & 127;

    for (int x = t; x < 3072; x += 256) {
      const int m = x >> 10, rem = x & 1023, k = rem >> 3, c = rem & 7;
      const float* W = (m == 0) ? Wte1 : ((m == 1) ? Wte2 : Wte3);
      const int row = m * 8 + c;
      wpack[row * 136 + k] = f2b(W[rem]);
    }
    for (int x = t; x < 1024; x += 256) {
      const int row = 24 + (x >> 7), col = x & 127;
      wpack[row * 136 + col] = 0;
    }

    const float* erow = e + ((size_t)(b * N) + i) * N * E;
    const int lane = t & 63, wid = t >> 6;
    const int li = lane & 15, lk8 = (lane >> 4) * 8, lq4 = (lane >> 4) * 4;
    const int jt = wid & 1, ct = wid >> 1;

    for (int j0 = 0; j0 < N; j0 += 32) {
      __syncthreads();
      for (int x = t; x < 1024; x += 256) {
        const int r = x >> 5, seg = x & 31;
        const float4 v = *reinterpret_cast<const float4*>(
            &erow[(size_t)(j0 + r) * E + seg * 4]);
        ushort4 pk;
        pk.x = f2b(v.x); pk.y = f2b(v.y); pk.z = f2b(v.z); pk.w = f2b(v.w);
        *reinterpret_cast<ushort4*>(&ebuf[r * 136 + seg * 4]) = pk;
      }
      __syncthreads();
      f32x4 acc = {0.f, 0.f, 0.f, 0.f};
#pragma unroll
      for (int kt = 0; kt < 4; ++kt) {
        const int rw = ct * 16 + li, ra = jt * 16 + li;
        const bf16x8 wf = *reinterpret_cast<const bf16x8*>(
            &wpack[rw * 136 + kt * 32 + lk8]);
        const bf16x8 af = *reinterpret_cast<const bf16x8*>(
            &ebuf[ra * 136 + kt * 32 + lk8]);
        acc = __builtin_amdgcn_mfma_f32_16x16x32_bf16(wf, af, acc, 0, 0, 0);
      }
      const int c0 = ct * 16 + lq4;
      if (c0 < 24) {
        ushort4 pk;
        pk.x = f2b(acc[0]); pk.y = f2b(acc[1]);
        pk.z = f2b(acc[2]); pk.w = f2b(acc[3]);
        *reinterpret_cast<ushort4*>(&outl[(j0 + jt * 16 + li) * 32 + c0]) = pk;
      }
    }
    __syncthreads();
    for (int x = t; x < 384; x += 256) {
      const int m = x >> 7, j = x & 127;
      const u16x8 v = *reinterpret_cast<const u16x8*>(&outl[j * 32 + m * 8]);
      if (m == 0)
        *reinterpret_cast<u16x8*>(&te1T[(((size_t)(b * N) + j) * N + i) * CH]) = v;
      else if (m == 1)
        *reinterpret_cast<u16x8*>(&te2[(((size_t)(b * N) + i) * N + j) * CH]) = v;
      else
        *reinterpret_cast<u16x8*>(&te3[(((size_t)(b * N) + i) * N + j) * CH]) = v;
    }
  } else if (blk < 1024) {
    float* zrow = (float*)(smem);
    float* grow = (float*)(smem + 1024);
    const int bn = blk - 512;
    const int b = bn >> 7, n = bn & 127;

    for (int k = t; k < C; k += 256) zrow[k] = z[((size_t)(b * N) + n) * C + k];
    if (t < C / 2) grow[t] = g[(size_t)b * (C / 2) + t];
    __syncthreads();

    {
      const int o = t & 127;
      const float* W = (t < 128) ? Wm1 : Wm2;
      float acc = 0.f;
#pragma unroll 8
      for (int k = 0; k < C; ++k) acc += zrow[k] * W[(size_t)k * O + o];
      if (t < 128) {
        float mgacc = 0.f;
        for (int k = 0; k < C / 2; ++k) mgacc += grow[k] * Wmg[(size_t)k * O + o];
        acc += mgacc;
        ws[OFF_M1 + ((size_t)(b * N) + n) * O + o] = acc;
      } else {
        ws[OFF_M2 + ((size_t)(b * N) + n) * O + o] = acc;
      }
    }
    if (t < 128) {
      float acc = 0.f;
#pragma unroll 8
      for (int k = 0; k < C; ++k) acc += zrow[k] * WU1[(size_t)k * O + t];
      ws[OFF_ZU1 + ((size_t)(b * N) + n) * O + t] = acc;
    } else if (t < 152) {
      const int idx = t - 128;
      const int which = idx >> 3, c = idx & 7;
      const float* W = (which == 0) ? Wt1 : ((which == 1) ? Wt2 : Wt3);
      float acc = 0.f;
      for (int k = 0; k < C; ++k) acc += zrow[k] * W[(size_t)k * CH + c];
      const size_t off = (which == 0) ? OFF_T1 : ((which == 1) ? OFF_T2 : OFF_T3);
      ws[off + ((size_t)(b * N) + n) * CH + c] = acc;
    }
    if (n == 0 && t >= 152 && t < 160) {
      const int c = t - 152;
      float acc = 0.f;
      for (int k = 0; k < C / 2; ++k) acc += grow[k] * Wtg[(size_t)k * CH + c];
      ws[OFF_TG + (size_t)b * CH + c] = acc;
    }
  } else {
    const int which = blk - 1024;
    const float* W = (which == 0) ? Wme : ((which == 1) ? Wmlp1 : Wmlp2);
    unsigned short* dst = (unsigned short*)(ws + OFF_WT) + (size_t)which * O * E;
    for (int x = t; x < O * E; x += 256) {
      const int o = x >> 7, k = x & 127;
      dst[x] = f2b(W[(size_t)k * O + o]);
    }
  }
}

// ---------------------------------------------------------------------------
// Kernel B (main), 512 threads:
//  blocks [0,256): msgs weight-stationary: (b, ig, jg) -> 32 i-rows x 8 j's
//  blocks [256,512): tri: (b, kh, jt) -> 64 k-rows x 4 j's
// ---------------------------------------------------------------------------
__global__ __launch_bounds__(512) void k_main(
    const float* __restrict__ e, const void* __restrict__ msk,
    const float* __restrict__ WU3, const float* __restrict__ ws_c,
    float* __restrict__ ws, float* __restrict__ out_tri) {
  __shared__ __align__(16) char smem[33856];
  const int blk = blockIdx.x;
  const int t = threadIdx.x;

  if (blk < 256) {
    // ============== msgs branch ==============
    unsigned short* act0 = (unsigned short*)(smem);          // [32][136]
    unsigned short* act1 = (unsigned short*)(smem + 8704);   // [32][136]
    float* m2s = (float*)(smem + 17408);                     // [32][128]
    int* fmtp = (int*)(smem + 33792);
    const int jg = blk & 15, ig = (blk >> 4) & 3, b = blk >> 6;
    const int j0 = jg * 8, i0g = ig * 32;
    constexpr int LDK = 136;

    const int lane = t & 63, wid = t >> 6;  // wid = o-tile 0..7
    const int li = lane & 15;
    const int lk8 = (lane >> 4) * 8;
    const int lq4 = (lane >> 4) * 4;

    // mask dtype sniff
    if (t < 64) {
      const unsigned w = ((const unsigned*)msk)[t];
      const float f = __uint_as_float(w);
      const unsigned long long bad_int = __ballot(w > 1u);
      const unsigned long long bad_flt = __ballot(!(f == 0.f || f == 1.f));
      if (t == 0) *fmtp = (bad_int == 0ull) ? 0 : ((bad_flt == 0ull) ? 2 : 1);
    }

    // weight fragments -> registers (once per block)
    const unsigned short* wts = (const unsigned short*)(ws_c + OFF_WT);
    bf16x8 wf0[4], wf1[4], wf2[4];
#pragma unroll
    for (int kt = 0; kt < 4; ++kt) {
      const size_t off = (size_t)(wid * 16 + li) * E + kt * 32 + lk8;
      wf0[kt] = *reinterpret_cast<const bf16x8*>(&wts[off]);
      wf1[kt] = *reinterpret_cast<const bf16x8*>(&wts[(size_t)O * E + off]);
      wf2[kt] = *reinterpret_cast<const bf16x8*>(&wts[(size_t)2 * O * E + off]);
    }
    // m2 tile (j-invariant) -> LDS once
    for (int x = t; x < 32 * O; x += 512)
      m2s[x] = ws_c[OFF_M2 + ((size_t)(b * N) + i0g + (x >> 7)) * O + (x & 127)];
    __syncthreads();
    const int fmt = *fmtp;

    const int iA = i0g + li, iB = i0g + 16 + li;
    const int srow = t >> 3, sseg = t & 7;  // staging role (t < 256)

    // ---- initial prefetch for j0 ----
    float4 ev;
    if (t < 256)
      ev = *reinterpret_cast<const float4*>(
          &e[(((size_t)(b * N) + i0g + srow) * N + j0) * E + sseg * 4]);
    float4 m1c = *reinterpret_cast<const float4*>(
        &ws_c[OFF_M1 + ((size_t)(b * N) + j0) * O + wid * 16 + lq4]);
    int mkAc, mkBc;
    {
      const size_t ia = ((size_t)(b * N) + iA) * N + j0;
      const size_t ib = ((size_t)(b * N) + iB) * N + j0;
      if (fmt == 0) { mkAc = ((const int*)msk)[ia] != 0; mkBc = ((const int*)msk)[ib] != 0; }
      else if (fmt == 1) { mkAc = ((const unsigned char*)msk)[ia] != 0; mkBc = ((const unsigned char*)msk)[ib] != 0; }
      else { mkAc = ((const float*)msk)[ia] != 0.f; mkBc = ((const float*)msk)[ib] != 0.f; }
    }
    if (t < 256) {
      ushort4 pk;
      pk.x = f2b(ev.x); pk.y = f2b(ev.y); pk.z = f2b(ev.z); pk.w = f2b(ev.w);
      *reinterpret_cast<ushort4*>(&act0[srow * LDK + sseg * 4]) = pk;
    }
    __syncthreads();

    unsigned short* actc = act0;
    unsigned short* actn = act1;
    const int o0 = wid * 16 + lq4;

    for (int jj = 0; jj < 8; ++jj) {
      const int j = j0 + jj;
      const int jn = (jj < 7) ? j + 1 : j;

      bf16x8 af[2][4];
      f32x4 acc[2];

      // ===== layer 1 =====
#pragma unroll
      for (int it = 0; it < 2; ++it)
#pragma unroll
        for (int kt = 0; kt < 4; ++kt)
          af[it][kt] = *reinterpret_cast<const bf16x8*>(
              &actc[(it * 16 + li) * LDK + kt * 32 + lk8]);
      // prefetch next j (T14: issue early)
      if (t < 256)
        ev = *reinterpret_cast<const float4*>(
            &e[(((size_t)(b * N) + i0g + srow) * N + jn) * E + sseg * 4]);
      float4 m1n = *reinterpret_cast<const float4*>(
          &ws_c[OFF_M1 + ((size_t)(b * N) + jn) * O + o0]);
      int mkAn, mkBn;
      {
        const size_t ia = ((size_t)(b * N) + iA) * N + jn;
        const size_t ib = ((size_t)(b * N) + iB) * N + jn;
        if (fmt == 0) { mkAn = ((const int*)msk)[ia] != 0; mkBn = ((const int*)msk)[ib] != 0; }
        else if (fmt == 1) { mkAn = ((const unsigned char*)msk)[ia] != 0; mkBn = ((const unsigned char*)msk)[ib] != 0; }
        else { mkAn = ((const float*)msk)[ia] != 0.f; mkBn = ((const float*)msk)[ib] != 0.f; }
      }
      acc[0] = (f32x4){0.f, 0.f, 0.f, 0.f};
      acc[1] = (f32x4){0.f, 0.f, 0.f, 0.f};
#pragma unroll
      for (int kt = 0; kt < 4; ++kt) {
        acc[0] = __builtin_amdgcn_mfma_f32_16x16x32_bf16(wf0[kt], af[0][kt], acc[0], 0, 0, 0);
        acc[1] = __builtin_amdgcn_mfma_f32_16x16x32_bf16(wf0[kt], af[1][kt], acc[1], 0, 0, 0);
      }
      __syncthreads();
      // writeback 1: relu(mask*me + m2 + m1')
#pragma unroll
      for (int it = 0; it < 2; ++it) {
        const int i = it * 16 + li;
        const float mk = (it ? mkBc : mkAc) ? 1.f : 0.f;
        const float4 m2v = *reinterpret_cast<const float4*>(&m2s[i * O + o0]);
        ushort4 pk;
        pk.x = f2b(fmaxf(acc[it][0] * mk + m2v.x + m1c.x, 0.f));
        pk.y = f2b(fmaxf(acc[it][1] * mk + m2v.y + m1c.y, 0.f));
        pk.z = f2b(fmaxf(acc[it][2] * mk + m2v.z + m1c.z, 0.f));
        pk.w = f2b(fmaxf(acc[it][3] * mk + m2v.w + m1c.w, 0.f));
        *reinterpret_cast<ushort4*>(&actc[i * LDK + o0]) = pk;
      }
      __syncthreads();

      // ===== layer 2 =====
#pragma unroll
      for (int it = 0; it < 2; ++it)
#pragma unroll
        for (int kt = 0; kt < 4; ++kt)
          af[it][kt] = *reinterpret_cast<const bf16x8*>(
              &actc[(it * 16 + li) * LDK + kt * 32 + lk8]);
      acc[0] = (f32x4){0.f, 0.f, 0.f, 0.f};
      acc[1] = (f32x4){0.f, 0.f, 0.f, 0.f};
#pragma unroll
      for (int kt = 0; kt < 4; ++kt) {
        acc[0] = __builtin_amdgcn_mfma_f32_16x16x32_bf16(wf1[kt], af[0][kt], acc[0], 0, 0, 0);
        acc[1] = __builtin_amdgcn_mfma_f32_16x16x32_bf16(wf1[kt], af[1][kt], acc[1], 0, 0, 0);
      }
      __syncthreads();
#pragma unroll
      for (int it = 0; it < 2; ++it) {
        const int i = it * 16 + li;
        ushort4 pk;
        pk.x = f2b(fmaxf(acc[it][0], 0.f));
        pk.y = f2b(fmaxf(acc[it][1], 0.f));
        pk.z = f2b(fmaxf(acc[it][2], 0.f));
        pk.w = f2b(fmaxf(acc[it][3], 0.f));
        *reinterpret_cast<ushort4*>(&actc[i * LDK + o0]) = pk;
      }
      __syncthreads();

      // ===== layer 3 =====
#pragma unroll
      for (int it = 0; it < 2; ++it)
#pragma unroll
        for (int kt = 0; kt < 4; ++kt)
          af[it][kt] = *reinterpret_cast<const bf16x8*>(
              &actc[(it * 16 + li) * LDK + kt * 32 + lk8]);
      acc[0] = (f32x4){0.f, 0.f, 0.f, 0.f};
      acc[1] = (f32x4){0.f, 0.f, 0.f, 0.f};
#pragma unroll
      for (int kt = 0; kt < 4; ++kt) {
        acc[0] = __builtin_amdgcn_mfma_f32_16x16x32_bf16(wf2[kt], af[0][kt], acc[0], 0, 0, 0);
        acc[1] = __builtin_amdgcn_mfma_f32_16x16x32_bf16(wf2[kt], af[1][kt], acc[1], 0, 0, 0);
      }
      // stage next j into the other buffer (T14: write late)
      if (t < 256) {
        ushort4 pk;
        pk.x = f2b(ev.x); pk.y = f2b(ev.y); pk.z = f2b(ev.z); pk.w = f2b(ev.w);
        *reinterpret_cast<ushort4*>(&actn[srow * LDK + sseg * 4]) = pk;
      }
      // masked max over 32 rows + partial write
      {
        float v0 = fmaxf(mkAc ? acc[0][0] : NEGV, mkBc ? acc[1][0] : NEGV);
        float v1 = fmaxf(mkAc ? acc[0][1] : NEGV, mkBc ? acc[1][1] : NEGV);
        float v2 = fmaxf(mkAc ? acc[0][2] : NEGV, mkBc ? acc[1][2] : NEGV);
        float v3 = fmaxf(mkAc ? acc[0][3] : NEGV, mkBc ? acc[1][3] : NEGV);
#pragma unroll
        for (int off = 1; off < 16; off <<= 1) {
          v0 = fmaxf(v0, __shfl_xor(v0, off));
          v1 = fmaxf(v1, __shfl_xor(v1, off));
          v2 = fmaxf(v2, __shfl_xor(v2, off));
          v3 = fmaxf(v3, __shfl_xor(v3, off));
        }
        if (li == 0) {
          float* part = ws + OFF_PART + (((size_t)(b * N) + j) * 4 + ig) * O;
          *reinterpret_cast<float4*>(&part[o0]) = make_float4(v0, v1, v2, v3);
        }
      }
      __syncthreads();
      // rotate
      unsigned short* tmp = actc; actc = actn; actn = tmp;
      m1c = m1n; mkAc = mkAn; mkBc = mkBn;
    }
  } else {
    // ============== tri branch: (b, kh, jt->4 j's), 512 threads ==============
    float* A4   = (float*)(smem);            // [4][128][8] f32
    float* wu3  = (float*)(smem + 16384);    // [8][128] f32
    float* trif = (float*)(smem + 20480);    // [4][64][8] f32
    float* t2j4 = (float*)(smem + 28672);    // [4][8]
    float* tgb  = (float*)(smem + 28800);    // [8]
    const int blk2 = blk - 256;
    const int kh = blk2 & 1, jt = (blk2 >> 1) & 31, b = blk2 >> 6;
    const int j0 = jt * 4;

    const unsigned short* te1T = (const unsigned short*)(ws_c + OFF_TE1T);
    const unsigned short* te2p =
        (const unsigned short*)(ws_c + OFF_TE2) + (size_t)b * N * N * CH;
    const unsigned short* te3p = (const unsigned short*)(ws_c + OFF_TE3);
    const float* t1p = ws_c + OFF_T1 + (size_t)b * N * CH;
    const float* t3p = ws_c + OFF_T3 + (size_t)b * N * CH;

    {
      const int idx8 = t * 8;
      const int jj = idx8 >> 10, i = (idx8 & 1023) >> 3;
      const u16x8 tv = *reinterpret_cast<const u16x8*>(
          &te1T[((size_t)(b * N) + j0 + jj) * N * CH + i * 8]);
      const float4 t1a = *reinterpret_cast<const float4*>(&t1p[i * 8]);
      const float4 t1b = *reinterpret_cast<const float4*>(&t1p[i * 8 + 4]);
      float4 av0, av1;
      av0.x = b2f(tv[0]) + t1a.x; av0.y = b2f(tv[1]) + t1a.y;
      av0.z = b2f(tv[2]) + t1a.z; av0.w = b2f(tv[3]) + t1a.w;
      av1.x = b2f(tv[4]) + t1b.x; av1.y = b2f(tv[5]) + t1b.y;
      av1.z = b2f(tv[6]) + t1b.z; av1.w = b2f(tv[7]) + t1b.w;
      *reinterpret_cast<float4*>(&A4[idx8]) = av0;
      *reinterpret_cast<float4*>(&A4[idx8 + 4]) = av1;
    }
    if (t < 256)
      *reinterpret_cast<float4*>(&wu3[t * 4]) =
          *reinterpret_cast<const float4*>(&WU3[t * 4]);
    if (t < 32)
      t2j4[t] = ws_c[OFF_T2 + ((size_t)(b * N) + j0 + (t >> 3)) * CH + (t & 7)];
    if (t < 8) tgb[t] = ws_c[OFF_TG + (size_t)b * CH + t];
    __syncthreads();

    const int io = t & 7, kl = t >> 3;  // kl 0..63
    const int kg = kh * 64 + kl;
    const size_t kbase = (size_t)kg * CH;
    float core[4][8];
#pragma unroll
    for (int jj = 0; jj < 4; ++jj)
#pragma unroll
      for (int c = 0; c < 8; ++c) core[jj][c] = -3.0e38f;

#pragma unroll 2
    for (int i0 = 0; i0 < N; i0 += 8) {
      const int i = i0 + io;
      const u16x8 rv =
          *reinterpret_cast<const u16x8*>(&te2p[(size_t)i * N * CH + kbase]);
      float r[8];
#pragma unroll
      for (int c = 0; c < 8; ++c) r[c] = b2f(rv[c]);
#pragma unroll
      for (int jj = 0; jj < 4; ++jj) {
        const float4 a0 = *reinterpret_cast<const float4*>(&A4[jj * 1024 + i * 8]);
        const float4 a1 = *reinterpret_cast<const float4*>(&A4[jj * 1024 + i * 8 + 4]);
        core[jj][0] = fmaxf(core[jj][0], a0.x + r[0]);
        core[jj][1] = fmaxf(core[jj][1], a0.y + r[1]);
        core[jj][2] = fmaxf(core[jj][2], a0.z + r[2]);
        core[jj][3] = fmaxf(core[jj][3], a0.w + r[3]);
        core[jj][4] = fmaxf(core[jj][4], a1.x + r[4]);
        core[jj][5] = fmaxf(core[jj][5], a1.y + r[5]);
        core[jj][6] = fmaxf(core[jj][6], a1.z + r[6]);
        core[jj][7] = fmaxf(core[jj][7], a1.w + r[7]);
      }
    }
#pragma unroll
    for (int jj = 0; jj < 4; ++jj)
#pragma unroll
      for (int c = 0; c < 8; ++c) {
        core[jj][c] = fmaxf(core[jj][c], __shfl_xor(core[jj][c], 1));
        core[jj][c] = fmaxf(core[jj][c], __shfl_xor(core[jj][c], 2));
        core[jj][c] = fmaxf(core[jj][c], __shfl_xor(core[jj][c], 4));
      }
#pragma unroll
    for (int jj = 0; jj < 4; ++jj) {
      float cv = core[jj][0];
#pragma unroll
      for (int c = 1; c < 8; ++c) cv = (io == c) ? core[jj][c] : cv;
      const unsigned short t3e =
          te3p[((size_t)(b * N) + j0 + jj) * N * CH + kbase + io];
      trif[jj * 512 + kl * 8 + io] =
          cv + t2j4[jj * 8 + io] + t3p[kbase + io] + b2f(t3e) + tgb[io];
    }
    __syncthreads();

    const int o = t & 127, rh = t >> 7;  // rh 0..3
    float wcol[8];
#pragma unroll
    for (int c = 0; c < 8; ++c) wcol[c] = wu3[c * 128 + o];
#pragma unroll 4
    for (int q = 0; q < 64; ++q) {
      const int row = q * 4 + rh;  // 0..255 = jj*64 + klr
      const int jj = row >> 6, klr = row & 63;
      const float4 f0 = *reinterpret_cast<const float4*>(&trif[row * 8]);
      const float4 f1 = *reinterpret_cast<const float4*>(&trif[row * 8 + 4]);
      float acc2 = f0.x * wcol[0] + f0.y * wcol[1] + f0.z * wcol[2] +
                   f0.w * wcol[3] + f1.x * wcol[4] + f1.y * wcol[5] +
                   f1.z * wcol[6] + f1.w * wcol[7];
      out_tri[((size_t)(b * N) + j0 + jj) * N * O +
              (size_t)(kh * 64 + klr) * O + o] = acc2;
    }
  }
}

// ---------------------------------------------------------------------------
// Kernel C: finalize msgs + ret (unchanged)
// ---------------------------------------------------------------------------
__global__ __launch_bounds__(256) void k_fin(
    const float* __restrict__ WU2, const float* __restrict__ ws,
    float* __restrict__ out_ret, float* __restrict__ out_msgs) {
  const int blk = blockIdx.x;
  const int b = blk >> 7, j = blk & 127;
  const int t = threadIdx.x;
  __shared__ float msgsrow[O];
  __shared__ float red[2][O];

  const float* part = ws + OFF_PART + ((size_t)(b * N) + j) * 4 * O;
  if (t < O) {
    const float m = fmaxf(fmaxf(part[t], part[O + t]),
                          fmaxf(part[2 * O + t], part[3 * O + t]));
    msgsrow[t] = m;
    out_msgs[((size_t)(b * N) + j) * O + t] = m;
  }
  __syncthreads();

  const int o = t & 127, h = t >> 7;
  float acc = 0.f;
#pragma unroll 8
  for (int p = h * 64; p < h * 64 + 64; ++p)
    acc += msgsrow[p] * WU2[(size_t)p * O + o];
  red[h][o] = acc;
  __syncthreads();
  if (t < O) {
    out_ret[((size_t)(b * N) + j) * O + t] =
        ws[OFF_ZU1 + ((size_t)(b * N) + j) * O + t] + red[0][t] + red[1][t];
  }
}

// ---------------------------------------------------------------------------
extern "C" void kernel_launch(void* const* d_in, const int* in_sizes, int n_in,
                              void* d_out, int out_size, void* d_ws,
                              size_t ws_size, hipStream_t stream) {
  const float* z    = (const float*)d_in[0];
  const float* e    = (const float*)d_in[1];
  const float* g    = (const float*)d_in[2];
  const void*  mmsk = d_in[4];
  const float* Wt1  = (const float*)d_in[5];
  const float* Wt2  = (const float*)d_in[6];
  const float* Wt3  = (const float*)d_in[7];
  const float* Wte1 = (const float*)d_in[8];
  const float* Wte2 = (const float*)d_in[9];
  const float* Wte3 = (const float*)d_in[10];
  const float* Wtg  = (const float*)d_in[11];
  const float* Wm1  = (const float*)d_in[12];
  const float* Wm2  = (const float*)d_in[13];
  const float* Wme  = (const float*)d_in[14];
  const float* Wmg  = (const float*)d_in[15];
  const float* Wmlp1= (const float*)d_in[16];
  const float* Wmlp2= (const float*)d_in[17];
  const float* WU1  = (const float*)d_in[18];
  const float* WU2  = (const float*)d_in[19];
  const float* WU3  = (const float*)d_in[20];

  float* ws = (float*)d_ws;
  float* out_ret  = (float*)d_out;
  float* out_msgs = out_ret + (size_t)B * N * O;
  float* out_tri  = out_msgs + (size_t)B * N * O;

  k_prep<<<1027, dim3(256), 0, stream>>>(z, g, e, Wt1, Wt2, Wt3, Wtg, Wm1, Wm2,
                                         Wmg, WU1, Wte1, Wte2, Wte3, Wme, Wmlp1,
                                         Wmlp2, ws);
  k_main<<<512, dim3(512), 0, stream>>>(e, mmsk, WU3, ws, ws, out_tri);
  k_fin<<<B * N, dim3(256), 0, stream>>>(WU2, ws, out_ret, out_msgs);
}